// Round 6
// baseline (74.234 us; speedup 1.0000x reference)
//
#include <hip/hip_runtime.h>

// GraphEmbeddings interaction network — swapped-operand MFMA, in-register
// layer handoff. B=64, P=128, F=16. One wave per (b, receiver p).
// fr1/fr2 computed as C^T = W^T_scaled · E^T  (A = prepacked weights, B = edge
// features). fr2's K-dim is permuted by sigma(ks,g,j) = (2ks+(j>>2))*16+4g+(j&3)
// on BOTH operands so the fr1 output registers feed fr2 directly (no LDS/shuffle).
// BN scales folded into weights at prep; biases added in-register.

#define NB 64
#define NF 16
#define NP 128

typedef _Float16 f16x8 __attribute__((ext_vector_type(8)));
typedef _Float16 f16x2 __attribute__((ext_vector_type(2)));
typedef float    f32x4 __attribute__((ext_vector_type(4)));

#define LGKM0() asm volatile("s_waitcnt lgkmcnt(0)" ::: "memory"); \
                __builtin_amdgcn_sched_barrier(0)

union U8 { f16x2 h[4]; f16x8 v; };

__device__ __forceinline__ f16x2 cvt_pk(float a, float b) {
    return __builtin_bit_cast(f16x2, __builtin_amdgcn_cvt_pkrtz(a, b));
}

// ---------------- prep: Rc/Sc partials + BN folds + weight packs ----------
// blocks 0..1535: per-node Rc/Sc (BN0 folded), fp16
// block 1536: cs consts (c2, fo0, fo1) + c1h (fp16 c1)
// blocks 1537..1568: pack W1^T (s1-scaled) and W2^T (sigma-permuted, s2-scaled)
__global__ void rs_prep_kernel(const float* __restrict__ x, const float* __restrict__ w0,
                               const float* __restrict__ w1, const float* __restrict__ w2,
                               _Float16* __restrict__ w1f, _Float16* __restrict__ w2f,
                               float* __restrict__ cs, _Float16* __restrict__ c1h,
                               _Float16* __restrict__ Rch, _Float16* __restrict__ Sch,
    const float* b0, const float* g0, const float* be0, const float* m0, const float* v0,
    const float* b1, const float* g1, const float* be1, const float* m1, const float* v1,
    const float* b2, const float* g2, const float* be2, const float* m2, const float* v2,
    const float* b3, const float* g3, const float* be3, const float* m3, const float* v3,
    const float* b4, const float* g4, const float* be4, const float* m4, const float* v4)
{
    const int bi = blockIdx.x;
    const int t = threadIdx.x;
    if (bi < 1536) {
        int idx = bi * 256 + t;            // B*P*48 (2 ch per thread)
        int c2 = idx % 48;
        int node = idx / 48;
        int p = node & (NP - 1);
        int b = node >> 7;
        int ch0 = c2 * 2, ch1 = c2 * 2 + 1;
        float sa = g0[ch0] * rsqrtf(v0[ch0] + 1e-3f);
        float sb = g0[ch1] * rsqrtf(v0[ch1] + 1e-3f);
        float ca = (b0[ch0] - m0[ch0]) * sa + be0[ch0];
        float cb = (b0[ch1] - m0[ch1]) * sb + be0[ch1];
        const float* xb = x + b * NF * NP + p;
        float r0 = 0.f, r1 = 0.f, s0 = 0.f, s1 = 0.f;
#pragma unroll
        for (int f = 0; f < NF; ++f) {
            float xv = xb[f * NP];
            float2 wr = *(const float2*)&w0[f * 96 + ch0];
            float2 ws = *(const float2*)&w0[(NF + f) * 96 + ch0];
            r0 += xv * wr.x; r1 += xv * wr.y;
            s0 += xv * ws.x; s1 += xv * ws.y;
        }
        f16x2 rv; rv[0] = (_Float16)(r0 * sa + ca); rv[1] = (_Float16)(r1 * sb + cb);
        f16x2 sv; sv[0] = (_Float16)(s0 * sa);      sv[1] = (_Float16)(s1 * sb);
        *(f16x2*)&Rch[idx * 2] = rv;
        *(f16x2*)&Sch[idx * 2] = sv;
    } else if (bi == 1536) {
        if (t < 64) {   // c1 (fp16, packed use) — s1 lives in W1
            float s = g1[t] * rsqrtf(v1[t] + 1e-3f);
            c1h[t] = (_Float16)((b1[t] - m1[t]) * s + be1[t]);
        }
        if (t < 32) {   // c2 — s2 lives in W2
            float s = g2[t] * rsqrtf(v2[t] + 1e-3f);
            cs[352 + t] = (b2[t] - m2[t]) * s + be2[t];
        }
        if (t < 64) {
            float s = g3[t] * rsqrtf(v3[t] + 1e-3f);
            cs[384 + t] = s; cs[448 + t] = (b3[t] - m3[t]) * s + be3[t];
        }
        if (t < 32) {
            float s = g4[t] * rsqrtf(v4[t] + 1e-3f);
            cs[512 + t] = s; cs[544 + t] = (b4[t] - m4[t]) * s + be4[t];
        }
    } else {
        int i = (bi - 1537) * 256 + t;        // 0..8191
        if (i < 6144) {                       // w1f[kb][n][j] = W1[kb*8+j][n]*s1[n]
            int j = i & 7, n = (i >> 3) & 63, kb = i >> 9;
            float s1 = g1[n] * rsqrtf(v1[n] + 1e-3f);
            w1f[i] = (_Float16)(w1[(kb * 8 + j) * 64 + n] * s1);
        } else {                              // w2f: sigma-permuted K, s2-scaled
            int i2 = i - 6144;
            int j = i2 & 7, n = (i2 >> 3) & 31, kb = i2 >> 8;
            int ks = kb >> 2, g = kb & 3;
            int src = (2 * ks + (j >> 2)) * 16 + 4 * g + (j & 3);
            float s2 = g2[n] * rsqrtf(v2[n] + 1e-3f);
            w2f[i2] = (_Float16)(w2[src * 32 + n] * s2);
        }
    }
}

// ---------------- edge MLP + fo, one wave per receiver ----------------
// Grid: 64 b x 32 groups = 2048 blocks, 256 threads = 4 waves = 4 receivers.
__global__ __launch_bounds__(256) void edge_fused(
    const _Float16* __restrict__ Rch, const _Float16* __restrict__ Sch,
    const _Float16* __restrict__ w1f,      // w1f (6144) || w2f (2048), contiguous
    const _Float16* __restrict__ c1h,
    const float* __restrict__ cs, const float* __restrict__ x,
    const float* __restrict__ fo0w, const float* __restrict__ fo1w,
    float* __restrict__ fo_out)
{
    __shared__ _Float16 WL[8192];      // staged W1^T/W2^T fragments (16 KB)
    __shared__ float    HW[4][116];    // wave-private fo scratch

    const int tid  = threadIdx.x;
    const int w    = tid >> 6;
    const int lane = tid & 63;
    const int g    = lane >> 4;
    const int l15  = lane & 15;
    const int blk  = blockIdx.x;
    const int b    = blk >> 5;
    const int p    = (blk & 31) * 4 + w;

    // stage weights to LDS (shared by all 4 waves)
    {
        const float4* src = (const float4*)w1f;
        float4* dst = (float4*)WL;
#pragma unroll
        for (int i = 0; i < 4; ++i) dst[tid + i * 256] = src[tid + i * 256];
    }
    __syncthreads();

    // per-lane constants
    f16x8 rc[3];
#pragma unroll
    for (int ks = 0; ks < 3; ++ks)
        rc[ks] = *(const f16x8*)&Rch[(size_t)(b * NP + p) * 96 + ks * 32 + g * 8];
    f16x2 c1pk[4][2];
#pragma unroll
    for (int mt = 0; mt < 4; ++mt)
#pragma unroll
        for (int rp = 0; rp < 2; ++rp)
            c1pk[mt][rp] = *(const f16x2*)&c1h[mt * 16 + 4 * g + 2 * rp];
    f32x4 c2v[2];
#pragma unroll
    for (int mt = 0; mt < 2; ++mt)
        c2v[mt] = *(const f32x4*)&cs[352 + mt * 16 + 4 * g];

    const _Float16* Sb = Sch + (size_t)b * NP * 96;
    f32x4 sums[2];
    sums[0] = (f32x4){0.f, 0.f, 0.f, 0.f};
    sums[1] = (f32x4){0.f, 0.f, 0.f, 0.f};

#pragma unroll
    for (int chunk = 0; chunk < 4; ++chunk) {
        // ---- B-frags of E1^T: straight from global, relu(rc + sv) ----
        f16x8 bf[2][3];
#pragma unroll
        for (int nt = 0; nt < 2; ++nt)
#pragma unroll
            for (int ks = 0; ks < 3; ++ks) {
                f16x8 sv = *(const f16x8*)&Sb[(chunk * 32 + nt * 16 + l15) * 96 + ks * 32 + g * 8];
                f16x8 tv = sv + rc[ks];
                f16x8 zz = {};
                bf[nt][ks] = __builtin_elementwise_max(tv, zz);
            }

        // ---- fr1: C1^T[mt][nt] = W1^T_s1 x E1^T ----
        f32x4 acc[4][2];
#pragma unroll
        for (int mt = 0; mt < 4; ++mt)
#pragma unroll
            for (int nt = 0; nt < 2; ++nt) acc[mt][nt] = (f32x4){0.f, 0.f, 0.f, 0.f};
#pragma unroll
        for (int ks = 0; ks < 3; ++ks)
#pragma unroll
            for (int mt = 0; mt < 4; ++mt) {
                f16x8 a1 = *(const f16x8*)&WL[(((ks * 4 + g) * 64) + mt * 16 + l15) * 8];
#pragma unroll
                for (int nt = 0; nt < 2; ++nt)
                    acc[mt][nt] = __builtin_amdgcn_mfma_f32_16x16x32_f16(a1, bf[nt][ks], acc[mt][nt], 0, 0, 0);
            }

        // ---- epilogue 1 (packed fp16): E2 words = relu(cvt(acc) + c1) ----
        f16x2 pw[4][2][2];
#pragma unroll
        for (int mt = 0; mt < 4; ++mt)
#pragma unroll
            for (int nt = 0; nt < 2; ++nt)
#pragma unroll
                for (int rp = 0; rp < 2; ++rp) {
                    f16x2 h = cvt_pk(acc[mt][nt][2 * rp], acc[mt][nt][2 * rp + 1]);
                    h = h + c1pk[mt][rp];
                    f16x2 zz = {};
                    pw[mt][nt][rp] = __builtin_elementwise_max(h, zz);
                }

        // ---- fr2: sigma-permuted K -> B-frag is the lane's own words ----
        f16x8 af[2][2];
#pragma unroll
        for (int ks = 0; ks < 2; ++ks)
#pragma unroll
            for (int nt = 0; nt < 2; ++nt) {
                U8 u;
                u.h[0] = pw[2 * ks][nt][0];
                u.h[1] = pw[2 * ks][nt][1];
                u.h[2] = pw[2 * ks + 1][nt][0];
                u.h[3] = pw[2 * ks + 1][nt][1];
                af[ks][nt] = u.v;
            }
        f32x4 acc2[2][2];
#pragma unroll
        for (int mt = 0; mt < 2; ++mt)
#pragma unroll
            for (int nt = 0; nt < 2; ++nt) acc2[mt][nt] = (f32x4){0.f, 0.f, 0.f, 0.f};
#pragma unroll
        for (int ks = 0; ks < 2; ++ks)
#pragma unroll
            for (int mt = 0; mt < 2; ++mt) {
                f16x8 a2 = *(const f16x8*)&WL[6144 + (((ks * 4 + g) * 32) + mt * 16 + l15) * 8];
#pragma unroll
                for (int nt = 0; nt < 2; ++nt)
                    acc2[mt][nt] = __builtin_amdgcn_mfma_f32_16x16x32_f16(a2, af[ks][nt], acc2[mt][nt], 0, 0, 0);
            }

        // ---- epilogue 2: relu(C2 + c2), accumulate senders != p ----
#pragma unroll
        for (int mt = 0; mt < 2; ++mt)
#pragma unroll
            for (int nt = 0; nt < 2; ++nt) {
                int e = chunk * 32 + nt * 16 + l15;
#pragma unroll
                for (int r = 0; r < 4; ++r) {
                    float v = fmaxf(acc2[mt][nt][r] + c2v[mt][r], 0.f);
                    sums[mt][r] += (e != p) ? v : 0.f;
                }
            }
    }

    // ---- reduce over the 16 edge-lanes within each group ----
#pragma unroll
    for (int mt = 0; mt < 2; ++mt)
#pragma unroll
        for (int d = 1; d <= 8; d <<= 1) {
            sums[mt][0] += __shfl_xor(sums[mt][0], d, 64);
            sums[mt][1] += __shfl_xor(sums[mt][1], d, 64);
            sums[mt][2] += __shfl_xor(sums[mt][2], d, 64);
            sums[mt][3] += __shfl_xor(sums[mt][3], d, 64);
        }

    // ---- fused fo MLP, wave-private ----
    float* hw = &HW[w][0];
    if (l15 == 0) {
        *(f32x4*)&hw[16 + 0 * 16 + 4 * g] = sums[0];
        *(f32x4*)&hw[16 + 1 * 16 + 4 * g] = sums[1];
    }
    if (lane < 16) hw[lane] = x[(b * NF + lane) * NP + p];
    LGKM0();

    float a1 = 0.f;
#pragma unroll 16
    for (int k = 0; k < 48; ++k) a1 += hw[k] * fo0w[k * 64 + lane];
    hw[48 + lane] = fmaxf(a1 * cs[384 + lane] + cs[448 + lane], 0.f);
    LGKM0();

    if (lane < 32) {
        float a2 = 0.f;
#pragma unroll 16
        for (int k = 0; k < 64; ++k) a2 += hw[48 + k] * fo1w[k * 32 + lane];
        fo_out[(size_t)(b * NP + p) * 32 + lane] =
            fmaxf(a2 * cs[512 + lane] + cs[544 + lane], 0.f);
    }
}

// ---------------- deterministic sum over nodes ----------------
__global__ void reduce_kernel(const float* __restrict__ fo_out, float* __restrict__ out) {
    int b = blockIdx.x;              // 64 blocks
    int t = threadIdx.x;             // 256
    int m = t & 31;
    int g = t >> 5;                  // 8 groups
    float v = 0.f;
    for (int p = g; p < NP; p += 8) v += fo_out[(b * NP + p) * 32 + m];
    __shared__ float red[256];
    red[t] = v;
    __syncthreads();
    for (int s = 4; s >= 1; s >>= 1) {
        if (g < s) red[t] += red[t + s * 32];
        __syncthreads();
    }
    if (g == 0) out[b * 32 + m] = red[t];
}

extern "C" void kernel_launch(void* const* d_in, const int* in_sizes, int n_in,
                              void* d_out, int out_size, void* d_ws, size_t ws_size,
                              hipStream_t stream) {
    (void)in_sizes; (void)n_in; (void)out_size; (void)ws_size;
    const float* x    = (const float*)d_in[0];
    const float* fr0w = (const float*)d_in[1];
    const float* fr1w = (const float*)d_in[7];
    const float* fr2w = (const float*)d_in[13];
    const float* fo0w = (const float*)d_in[19];
    const float* fo1w = (const float*)d_in[25];

    float* ws = (float*)d_ws;
    float*    cs     = ws;                                   // 1024 f32
    _Float16* Rch    = (_Float16*)(ws + 1024);               // 786432 fp16
    _Float16* Sch    = (_Float16*)(ws + 1024 + 393216);      // 786432 fp16
    _Float16* w1f    = (_Float16*)(ws + 787456);             // 6144 fp16
    _Float16* w2f    = (_Float16*)(ws + 787456 + 3072);      // 2048 fp16 (contiguous!)
    _Float16* c1h    = (_Float16*)(ws + 791552);             // 64 fp16
    float*    fo_out = ws + 791616;                          // B*P*32 f32
    float*    out    = (float*)d_out;

    rs_prep_kernel<<<1569, 256, 0, stream>>>(x, fr0w, fr1w, fr2w, w1f, w2f, cs, c1h, Rch, Sch,
        (const float*)d_in[2],  (const float*)d_in[3],  (const float*)d_in[4],
        (const float*)d_in[5],  (const float*)d_in[6],
        (const float*)d_in[8],  (const float*)d_in[9],  (const float*)d_in[10],
        (const float*)d_in[11], (const float*)d_in[12],
        (const float*)d_in[14], (const float*)d_in[15], (const float*)d_in[16],
        (const float*)d_in[17], (const float*)d_in[18],
        (const float*)d_in[20], (const float*)d_in[21], (const float*)d_in[22],
        (const float*)d_in[23], (const float*)d_in[24],
        (const float*)d_in[26], (const float*)d_in[27], (const float*)d_in[28],
        (const float*)d_in[29], (const float*)d_in[30]);

    edge_fused<<<NB * 32, 256, 0, stream>>>(Rch, Sch, w1f, c1h, cs, x, fo0w, fo1w, fo_out);

    reduce_kernel<<<NB, 256, 0, stream>>>(fo_out, out);
}

// Round 7
// 73.766 us; speedup vs baseline: 1.0063x; 1.0063x over previous
//
#include <hip/hip_runtime.h>

// GraphEmbeddings interaction network — swapped-operand MFMA, in-register
// fr1->fr2 handoff (sigma-permuted K), coalesced Sc k-planes, per-block fo.
// B=64, P=128, F=16. One wave per (b, receiver p); 4 receivers per block.
// Weights live in registers; fo MLP runs once per block on wave 0 via the
// same swapped-MFMA trick (nodes on l15). agg never goes to global.

#define NB 64
#define NF 16
#define NP 128

typedef _Float16 f16x8 __attribute__((ext_vector_type(8)));
typedef _Float16 f16x2 __attribute__((ext_vector_type(2)));
typedef float    f32x4 __attribute__((ext_vector_type(4)));

union U8 { f16x2 h[4]; f16x8 v; };

__device__ __forceinline__ f16x2 cvt_pk(float a, float b) {
    return __builtin_bit_cast(f16x2, __builtin_amdgcn_cvt_pkrtz(a, b));
}

// ---------------- prep ----------------
// blocks 0..1535   : Rc (layout [node][96]) and Sc2 (k-planes [(b*3+ks)*128+a][32]), fp16
// block 1536       : consts c1h (fp16), c2 (cs+352), c3h (fp16), c4 (cs+512)
// blocks 1537..1568: w1f (W1^T s1-scaled frags) + w2f (sigma, s2-scaled)
// blocks 1569..1592: w3f (fo0^T s3-scaled, K 48->64 zero-pad) + w4f (sigma, s4)
// blocks 1593..1624: xt16[node][16] transpose of x
__global__ void prep_kernel(const float* __restrict__ x, const float* __restrict__ w0,
                            const float* __restrict__ w1, const float* __restrict__ w2,
                            const float* __restrict__ w3, const float* __restrict__ w4,
                            _Float16* __restrict__ w1f, _Float16* __restrict__ w3f,
                            float* __restrict__ cs, _Float16* __restrict__ c1h,
                            _Float16* __restrict__ c3h, _Float16* __restrict__ xt16,
                            _Float16* __restrict__ Rch, _Float16* __restrict__ Sc2,
    const float* b0, const float* g0, const float* be0, const float* m0, const float* v0,
    const float* b1, const float* g1, const float* be1, const float* m1, const float* v1,
    const float* b2, const float* g2, const float* be2, const float* m2, const float* v2,
    const float* b3, const float* g3, const float* be3, const float* m3, const float* v3,
    const float* b4, const float* g4, const float* be4, const float* m4, const float* v4)
{
    const int bi = blockIdx.x;
    const int t = threadIdx.x;
    if (bi < 1536) {
        int idx = bi * 256 + t;            // B*P*48 (2 ch per thread)
        int c2i = idx % 48;
        int node = idx / 48;
        int p = node & (NP - 1);
        int b = node >> 7;
        int ch0 = c2i * 2, ch1 = ch0 + 1;
        float sa = g0[ch0] * rsqrtf(v0[ch0] + 1e-3f);
        float sb = g0[ch1] * rsqrtf(v0[ch1] + 1e-3f);
        float ca = (b0[ch0] - m0[ch0]) * sa + be0[ch0];
        float cb = (b0[ch1] - m0[ch1]) * sb + be0[ch1];
        const float* xb = x + b * NF * NP + p;
        float r0 = 0.f, r1 = 0.f, s0 = 0.f, s1 = 0.f;
#pragma unroll
        for (int f = 0; f < NF; ++f) {
            float xv = xb[f * NP];
            float2 wr = *(const float2*)&w0[f * 96 + ch0];
            float2 ws = *(const float2*)&w0[(NF + f) * 96 + ch0];
            r0 += xv * wr.x; r1 += xv * wr.y;
            s0 += xv * ws.x; s1 += xv * ws.y;
        }
        f16x2 rv; rv[0] = (_Float16)(r0 * sa + ca); rv[1] = (_Float16)(r1 * sb + cb);
        f16x2 sv; sv[0] = (_Float16)(s0 * sa);      sv[1] = (_Float16)(s1 * sb);
        *(f16x2*)&Rch[node * 96 + ch0] = rv;
        int ks = ch0 >> 5;                 // plane (pair stays within one plane)
        *(f16x2*)&Sc2[((b * 3 + ks) * NP + p) * 32 + (ch0 - ks * 32)] = sv;
    } else if (bi == 1536) {
        if (t < 64) {
            float s = g1[t] * rsqrtf(v1[t] + 1e-3f);
            c1h[t] = (_Float16)((b1[t] - m1[t]) * s + be1[t]);
        }
        if (t < 32) {
            float s = g2[t] * rsqrtf(v2[t] + 1e-3f);
            cs[352 + t] = (b2[t] - m2[t]) * s + be2[t];
        }
        if (t < 64) {
            float s = g3[t] * rsqrtf(v3[t] + 1e-3f);
            c3h[t] = (_Float16)((b3[t] - m3[t]) * s + be3[t]);
        }
        if (t < 32) {
            float s = g4[t] * rsqrtf(v4[t] + 1e-3f);
            cs[512 + t] = (b4[t] - m4[t]) * s + be4[t];
        }
    } else if (bi < 1569) {
        int i = (bi - 1537) * 256 + t;        // 0..8191
        if (i < 6144) {                       // w1f[kb][n][j] = W1[kb*8+j][n]*s1[n]
            int j = i & 7, n = (i >> 3) & 63, kb = i >> 9;
            float s1 = g1[n] * rsqrtf(v1[n] + 1e-3f);
            w1f[i] = (_Float16)(w1[(kb * 8 + j) * 64 + n] * s1);
        } else {                              // w2f: sigma-permuted K, s2-scaled
            int i2 = i - 6144;
            int j = i2 & 7, n = (i2 >> 3) & 31, kb = i2 >> 8;
            int ks = kb >> 2, g = kb & 3;
            int src = (2 * ks + (j >> 2)) * 16 + 4 * g + (j & 3);
            float s2 = g2[n] * rsqrtf(v2[n] + 1e-3f);
            w1f[6144 + i2] = (_Float16)(w2[src * 32 + n] * s2);
        }
    } else if (bi < 1593) {
        int i = (bi - 1569) * 256 + t;        // 0..6143
        if (i < 4096) {                       // w3f[kb][n][j] = fo0[kb*8+j][n]*s3[n], pad k>=48
            int j = i & 7, n = (i >> 3) & 63, kb = i >> 9;
            int k = kb * 8 + j;
            float s3 = g3[n] * rsqrtf(v3[n] + 1e-3f);
            w3f[i] = (k < 48) ? (_Float16)(w3[k * 64 + n] * s3) : (_Float16)0.f;
        } else {                              // w4f: sigma-permuted, s4-scaled
            int i2 = i - 4096;
            int j = i2 & 7, n = (i2 >> 3) & 31, kb = i2 >> 8;
            int ks = kb >> 2, g = kb & 3;
            int src = (2 * ks + (j >> 2)) * 16 + 4 * g + (j & 3);
            float s4 = g4[n] * rsqrtf(v4[n] + 1e-3f);
            w3f[4096 + i2] = (_Float16)(w4[src * 32 + n] * s4);
        }
    } else {
        int n = (bi - 1593) * 256 + t;        // 0..8191 nodes
        int b = n >> 7, pn = n & 127;
        _Float16 tmp[16];
#pragma unroll
        for (int f = 0; f < NF; ++f) tmp[f] = (_Float16)x[(b * NF + f) * NP + pn];
        *(f16x8*)&xt16[n * 16]     = *(f16x8*)&tmp[0];
        *(f16x8*)&xt16[n * 16 + 8] = *(f16x8*)&tmp[8];
    }
}

// ---------------- edge MLP + per-block fo ----------------
// Grid: 2048 blocks, 256 threads = 4 waves = 4 receivers (pbase..pbase+3).
__global__ __launch_bounds__(256) void edge_fused(
    const _Float16* __restrict__ Rch, const _Float16* __restrict__ Sc2,
    const _Float16* __restrict__ w1f,      // w1f(6144) || w2f(2048)
    const _Float16* __restrict__ w3f,      // w3f(4096) || w4f(2048)
    const _Float16* __restrict__ c1h, const _Float16* __restrict__ c3h,
    const float* __restrict__ cs, const _Float16* __restrict__ xt16,
    float* __restrict__ fo_out)
{
    __shared__ float    psum[4][32];
    __shared__ _Float16 Hl[16][72];

    const int tid  = threadIdx.x;
    const int w    = tid >> 6;
    const int lane = tid & 63;
    const int g    = lane >> 4;
    const int l15  = lane & 15;
    const int blk  = blockIdx.x;
    const int b    = blk >> 5;
    const int pbase = (blk & 31) * 4;
    const int p    = pbase + w;

    // ---- weights in registers ----
    f16x8 bw1[3][4];
#pragma unroll
    for (int ks = 0; ks < 3; ++ks)
#pragma unroll
        for (int mt = 0; mt < 4; ++mt)
            bw1[ks][mt] = *(const f16x8*)&w1f[(((ks * 4 + g) * 64) + mt * 16 + l15) * 8];
    f16x8 bw2[2][2];
#pragma unroll
    for (int ks = 0; ks < 2; ++ks)
#pragma unroll
        for (int mt = 0; mt < 2; ++mt)
            bw2[ks][mt] = *(const f16x8*)&w1f[6144 + (((ks * 4 + g) * 32) + mt * 16 + l15) * 8];

    f16x8 rc[3];
#pragma unroll
    for (int ks = 0; ks < 3; ++ks)
        rc[ks] = *(const f16x8*)&Rch[(size_t)(b * NP + p) * 96 + ks * 32 + g * 8];
    f16x2 c1pk[4][2];
#pragma unroll
    for (int mt = 0; mt < 4; ++mt)
#pragma unroll
        for (int rp = 0; rp < 2; ++rp)
            c1pk[mt][rp] = *(const f16x2*)&c1h[mt * 16 + 4 * g + 2 * rp];
    f32x4 c2v[2];
#pragma unroll
    for (int mt = 0; mt < 2; ++mt)
        c2v[mt] = *(const f32x4*)&cs[352 + mt * 16 + 4 * g];

    f32x4 sums[2];
    sums[0] = (f32x4){0.f, 0.f, 0.f, 0.f};
    sums[1] = (f32x4){0.f, 0.f, 0.f, 0.f};

#pragma unroll 2
    for (int chunk = 0; chunk < 4; ++chunk) {
        // ---- B-frags of E1^T from coalesced k-planes ----
        f16x8 bf[2][3];
#pragma unroll
        for (int nt = 0; nt < 2; ++nt)
#pragma unroll
            for (int ks = 0; ks < 3; ++ks) {
                int row = chunk * 32 + nt * 16 + l15;
                f16x8 sv = *(const f16x8*)&Sc2[(size_t)((b * 3 + ks) * NP + row) * 32 + g * 8];
                f16x8 tv = sv + rc[ks];
                f16x8 zz = {};
                bf[nt][ks] = __builtin_elementwise_max(tv, zz);
            }

        // ---- fr1: C1^T = W1^T x E1^T ----
        f32x4 acc[4][2];
#pragma unroll
        for (int mt = 0; mt < 4; ++mt)
#pragma unroll
            for (int nt = 0; nt < 2; ++nt) acc[mt][nt] = (f32x4){0.f, 0.f, 0.f, 0.f};
#pragma unroll
        for (int ks = 0; ks < 3; ++ks)
#pragma unroll
            for (int mt = 0; mt < 4; ++mt)
#pragma unroll
                for (int nt = 0; nt < 2; ++nt)
                    acc[mt][nt] = __builtin_amdgcn_mfma_f32_16x16x32_f16(bw1[ks][mt], bf[nt][ks], acc[mt][nt], 0, 0, 0);

        // ---- epilogue 1 (packed fp16) ----
        f16x2 pw[4][2][2];
#pragma unroll
        for (int mt = 0; mt < 4; ++mt)
#pragma unroll
            for (int nt = 0; nt < 2; ++nt)
#pragma unroll
                for (int rp = 0; rp < 2; ++rp) {
                    f16x2 h = cvt_pk(acc[mt][nt][2 * rp], acc[mt][nt][2 * rp + 1]);
                    h = h + c1pk[mt][rp];
                    f16x2 zz = {};
                    pw[mt][nt][rp] = __builtin_elementwise_max(h, zz);
                }

        // ---- fr2 via sigma handoff ----
        f32x4 acc2[2][2];
#pragma unroll
        for (int mt = 0; mt < 2; ++mt)
#pragma unroll
            for (int nt = 0; nt < 2; ++nt) acc2[mt][nt] = (f32x4){0.f, 0.f, 0.f, 0.f};
#pragma unroll
        for (int ks = 0; ks < 2; ++ks)
#pragma unroll
            for (int nt = 0; nt < 2; ++nt) {
                U8 u;
                u.h[0] = pw[2 * ks][nt][0];
                u.h[1] = pw[2 * ks][nt][1];
                u.h[2] = pw[2 * ks + 1][nt][0];
                u.h[3] = pw[2 * ks + 1][nt][1];
#pragma unroll
                for (int mt = 0; mt < 2; ++mt)
                    acc2[mt][nt] = __builtin_amdgcn_mfma_f32_16x16x32_f16(bw2[ks][mt], u.v, acc2[mt][nt], 0, 0, 0);
            }

        // ---- epilogue 2: relu(C2 + c2), accumulate senders != p ----
#pragma unroll
        for (int mt = 0; mt < 2; ++mt)
#pragma unroll
            for (int nt = 0; nt < 2; ++nt) {
                int e = chunk * 32 + nt * 16 + l15;
#pragma unroll
                for (int r = 0; r < 4; ++r) {
                    float v = fmaxf(acc2[mt][nt][r] + c2v[mt][r], 0.f);
                    sums[mt][r] += (e != p) ? v : 0.f;
                }
            }
    }

    // ---- reduce over the 16 edge-lanes within each group ----
#pragma unroll
    for (int mt = 0; mt < 2; ++mt)
#pragma unroll
        for (int d = 1; d <= 8; d <<= 1) {
            sums[mt][0] += __shfl_xor(sums[mt][0], d, 64);
            sums[mt][1] += __shfl_xor(sums[mt][1], d, 64);
            sums[mt][2] += __shfl_xor(sums[mt][2], d, 64);
            sums[mt][3] += __shfl_xor(sums[mt][3], d, 64);
        }
    if (l15 == 0) {
#pragma unroll
        for (int mt = 0; mt < 2; ++mt)
            *(f32x4*)&psum[w][mt * 16 + 4 * g] = sums[mt];
    }
    __syncthreads();

    // ---- build H rows for the block's 4 receivers ----
    if (tid < 128) {
        int node = tid >> 5, ch = tid & 31;
        Hl[node][16 + ch] = (_Float16)psum[node][ch];
    } else if (tid < 192) {
        int i = tid - 128, node = i >> 4, f = i & 15;
        Hl[node][f] = xt16[(size_t)(b * NP + pbase + node) * 16 + f];
    } else {
        int i = tid - 192, node = i >> 4;
        Hl[node][48 + (i & 15)] = (_Float16)0.f;
    }
    __syncthreads();

    // ---- fo MLP on wave 0 (nodes on l15; cols 4..15 are garbage, unstored) ----
    if (w == 0) {
        f16x8 bfo[2];
#pragma unroll
        for (int ks = 0; ks < 2; ++ks)
            bfo[ks] = *(const f16x8*)&Hl[l15][ks * 32 + g * 8];
        f32x4 acc3[4];
#pragma unroll
        for (int mt = 0; mt < 4; ++mt) acc3[mt] = (f32x4){0.f, 0.f, 0.f, 0.f};
#pragma unroll
        for (int ks = 0; ks < 2; ++ks)
#pragma unroll
            for (int mt = 0; mt < 4; ++mt) {
                f16x8 a3 = *(const f16x8*)&w3f[(((ks * 4 + g) * 64) + mt * 16 + l15) * 8];
                acc3[mt] = __builtin_amdgcn_mfma_f32_16x16x32_f16(a3, bfo[ks], acc3[mt], 0, 0, 0);
            }
        f16x2 pw3[4][2];
#pragma unroll
        for (int mt = 0; mt < 4; ++mt)
#pragma unroll
            for (int rp = 0; rp < 2; ++rp) {
                f16x2 h = cvt_pk(acc3[mt][2 * rp], acc3[mt][2 * rp + 1]);
                h = h + *(const f16x2*)&c3h[mt * 16 + 4 * g + 2 * rp];
                f16x2 zz = {};
                pw3[mt][rp] = __builtin_elementwise_max(h, zz);
            }
        f32x4 acc4[2];
        acc4[0] = (f32x4){0.f, 0.f, 0.f, 0.f};
        acc4[1] = (f32x4){0.f, 0.f, 0.f, 0.f};
#pragma unroll
        for (int ks = 0; ks < 2; ++ks) {
            U8 u;
            u.h[0] = pw3[2 * ks][0];
            u.h[1] = pw3[2 * ks][1];
            u.h[2] = pw3[2 * ks + 1][0];
            u.h[3] = pw3[2 * ks + 1][1];
#pragma unroll
            for (int mt = 0; mt < 2; ++mt) {
                f16x8 a4 = *(const f16x8*)&w3f[4096 + (((ks * 4 + g) * 32) + mt * 16 + l15) * 8];
                acc4[mt] = __builtin_amdgcn_mfma_f32_16x16x32_f16(a4, u.v, acc4[mt], 0, 0, 0);
            }
        }
        if (l15 < 4) {
#pragma unroll
            for (int mt = 0; mt < 2; ++mt) {
                f32x4 c4 = *(const f32x4*)&cs[512 + mt * 16 + 4 * g];
                f32x4 o;
#pragma unroll
                for (int r = 0; r < 4; ++r) o[r] = fmaxf(acc4[mt][r] + c4[r], 0.f);
                *(f32x4*)&fo_out[(size_t)(b * NP + pbase + l15) * 32 + mt * 16 + 4 * g] = o;
            }
        }
    }
}

// ---------------- deterministic sum over nodes ----------------
__global__ void reduce_kernel(const float* __restrict__ fo_out, float* __restrict__ out) {
    int b = blockIdx.x;              // 64 blocks
    int t = threadIdx.x;             // 256
    int m = t & 31;
    int g = t >> 5;                  // 8 groups
    float v = 0.f;
    for (int p = g; p < NP; p += 8) v += fo_out[(b * NP + p) * 32 + m];
    __shared__ float red[256];
    red[t] = v;
    __syncthreads();
    for (int s = 4; s >= 1; s >>= 1) {
        if (g < s) red[t] += red[t + s * 32];
        __syncthreads();
    }
    if (g == 0) out[b * 32 + m] = red[t];
}

extern "C" void kernel_launch(void* const* d_in, const int* in_sizes, int n_in,
                              void* d_out, int out_size, void* d_ws, size_t ws_size,
                              hipStream_t stream) {
    (void)in_sizes; (void)n_in; (void)out_size; (void)ws_size;
    const float* x    = (const float*)d_in[0];
    const float* fr0w = (const float*)d_in[1];
    const float* fr1w = (const float*)d_in[7];
    const float* fr2w = (const float*)d_in[13];
    const float* fo0w = (const float*)d_in[19];
    const float* fo1w = (const float*)d_in[25];

    float* ws = (float*)d_ws;
    float*    cs     = ws;                                   // 1024 f32
    _Float16* Rch    = (_Float16*)(ws + 1024);               // 786432 f16
    _Float16* Sc2    = (_Float16*)(ws + 394240);             // 786432 f16
    _Float16* w1f    = (_Float16*)(ws + 787456);             // 8192 f16 (w1f||w2f)
    _Float16* w3f    = (_Float16*)(ws + 791552);             // 6144 f16 (w3f||w4f)
    _Float16* c1h    = (_Float16*)(ws + 794624);             // 64 f16
    _Float16* c3h    = c1h + 64;                             // 64 f16
    _Float16* xt16   = (_Float16*)(ws + 794688);             // 131072 f16
    float*    fo_out = ws + 860224;                          // B*P*32 f32
    float*    out    = (float*)d_out;

    prep_kernel<<<1625, 256, 0, stream>>>(x, fr0w, fr1w, fr2w, fo0w, fo1w,
        w1f, w3f, cs, c1h, c3h, xt16, Rch, Sc2,
        (const float*)d_in[2],  (const float*)d_in[3],  (const float*)d_in[4],
        (const float*)d_in[5],  (const float*)d_in[6],
        (const float*)d_in[8],  (const float*)d_in[9],  (const float*)d_in[10],
        (const float*)d_in[11], (const float*)d_in[12],
        (const float*)d_in[14], (const float*)d_in[15], (const float*)d_in[16],
        (const float*)d_in[17], (const float*)d_in[18],
        (const float*)d_in[20], (const float*)d_in[21], (const float*)d_in[22],
        (const float*)d_in[23], (const float*)d_in[24],
        (const float*)d_in[26], (const float*)d_in[27], (const float*)d_in[28],
        (const float*)d_in[29], (const float*)d_in[30]);

    edge_fused<<<NB * 32, 256, 0, stream>>>(Rch, Sc2, w1f, w3f, c1h, c3h, cs, xt16, fo_out);

    reduce_kernel<<<NB, 256, 0, stream>>>(fo_out, out);
}

// Round 8
// 55.924 us; speedup vs baseline: 1.3274x; 1.3190x over previous
//
#include <hip/hip_runtime.h>

// GraphEmbeddings interaction network — swapped-operand MFMA, sigma in-register
// fr1->fr2 handoff, nt-streamed (low live-reg), bw2 via LDS, 2 waves/receiver.
// B=64, P=128, F=16. Grid: 4096 blocks x 256 thr; block = 2 receivers; each
// wave handles 64 edges of one receiver. fo MLP per block on wave 0.

#define NB 64
#define NF 16
#define NP 128

typedef _Float16 f16x8 __attribute__((ext_vector_type(8)));
typedef _Float16 f16x2 __attribute__((ext_vector_type(2)));
typedef float    f32x4 __attribute__((ext_vector_type(4)));

__device__ __forceinline__ f16x2 cvt_pk(float a, float b) {
    return __builtin_bit_cast(f16x2, __builtin_amdgcn_cvt_pkrtz(a, b));
}
__device__ __forceinline__ unsigned bc32(f16x2 h) {
    return __builtin_bit_cast(unsigned, h);
}

// ---------------- prep ----------------
// blocks 0..1535   : Rc ([node][96]) and Sc2 (k-planes [(b*3+ks)*128+a][32]), fp16
// block 1536       : consts c1h (fp16), c2 (cs+352), c3h (fp16), c4 (cs+512)
// blocks 1537..1568: w1f (W1^T s1-scaled frags) + w2f (sigma, s2-scaled)
// blocks 1569..1592: w3f (fo0^T s3-scaled, K 48->64 zero-pad) + w4f (sigma, s4)
// blocks 1593..1624: xt16[node][16] transpose of x
__global__ void prep_kernel(const float* __restrict__ x, const float* __restrict__ w0,
                            const float* __restrict__ w1, const float* __restrict__ w2,
                            const float* __restrict__ w3, const float* __restrict__ w4,
                            _Float16* __restrict__ w1f, _Float16* __restrict__ w3f,
                            float* __restrict__ cs, _Float16* __restrict__ c1h,
                            _Float16* __restrict__ c3h, _Float16* __restrict__ xt16,
                            _Float16* __restrict__ Rch, _Float16* __restrict__ Sc2,
    const float* b0, const float* g0, const float* be0, const float* m0, const float* v0,
    const float* b1, const float* g1, const float* be1, const float* m1, const float* v1,
    const float* b2, const float* g2, const float* be2, const float* m2, const float* v2,
    const float* b3, const float* g3, const float* be3, const float* m3, const float* v3,
    const float* b4, const float* g4, const float* be4, const float* m4, const float* v4)
{
    const int bi = blockIdx.x;
    const int t = threadIdx.x;
    if (bi < 1536) {
        int idx = bi * 256 + t;            // B*P*48 (2 ch per thread)
        int c2i = idx % 48;
        int node = idx / 48;
        int p = node & (NP - 1);
        int b = node >> 7;
        int ch0 = c2i * 2, ch1 = ch0 + 1;
        float sa = g0[ch0] * rsqrtf(v0[ch0] + 1e-3f);
        float sb = g0[ch1] * rsqrtf(v0[ch1] + 1e-3f);
        float ca = (b0[ch0] - m0[ch0]) * sa + be0[ch0];
        float cb = (b0[ch1] - m0[ch1]) * sb + be0[ch1];
        const float* xb = x + b * NF * NP + p;
        float r0 = 0.f, r1 = 0.f, s0 = 0.f, s1 = 0.f;
#pragma unroll
        for (int f = 0; f < NF; ++f) {
            float xv = xb[f * NP];
            float2 wr = *(const float2*)&w0[f * 96 + ch0];
            float2 ws = *(const float2*)&w0[(NF + f) * 96 + ch0];
            r0 += xv * wr.x; r1 += xv * wr.y;
            s0 += xv * ws.x; s1 += xv * ws.y;
        }
        f16x2 rv; rv[0] = (_Float16)(r0 * sa + ca); rv[1] = (_Float16)(r1 * sb + cb);
        f16x2 sv; sv[0] = (_Float16)(s0 * sa);      sv[1] = (_Float16)(s1 * sb);
        *(f16x2*)&Rch[node * 96 + ch0] = rv;
        int ks = ch0 >> 5;                 // plane (pair stays within one plane)
        *(f16x2*)&Sc2[((b * 3 + ks) * NP + p) * 32 + (ch0 - ks * 32)] = sv;
    } else if (bi == 1536) {
        if (t < 64) {
            float s = g1[t] * rsqrtf(v1[t] + 1e-3f);
            c1h[t] = (_Float16)((b1[t] - m1[t]) * s + be1[t]);
        }
        if (t < 32) {
            float s = g2[t] * rsqrtf(v2[t] + 1e-3f);
            cs[352 + t] = (b2[t] - m2[t]) * s + be2[t];
        }
        if (t < 64) {
            float s = g3[t] * rsqrtf(v3[t] + 1e-3f);
            c3h[t] = (_Float16)((b3[t] - m3[t]) * s + be3[t]);
        }
        if (t < 32) {
            float s = g4[t] * rsqrtf(v4[t] + 1e-3f);
            cs[512 + t] = (b4[t] - m4[t]) * s + be4[t];
        }
    } else if (bi < 1569) {
        int i = (bi - 1537) * 256 + t;        // 0..8191
        if (i < 6144) {                       // w1f[kb][n][j] = W1[kb*8+j][n]*s1[n]
            int j = i & 7, n = (i >> 3) & 63, kb = i >> 9;
            float s1 = g1[n] * rsqrtf(v1[n] + 1e-3f);
            w1f[i] = (_Float16)(w1[(kb * 8 + j) * 64 + n] * s1);
        } else {                              // w2f: sigma-permuted K, s2-scaled
            int i2 = i - 6144;
            int j = i2 & 7, n = (i2 >> 3) & 31, kb = i2 >> 8;
            int ks = kb >> 2, g = kb & 3;
            int src = (2 * ks + (j >> 2)) * 16 + 4 * g + (j & 3);
            float s2 = g2[n] * rsqrtf(v2[n] + 1e-3f);
            w1f[6144 + i2] = (_Float16)(w2[src * 32 + n] * s2);
        }
    } else if (bi < 1593) {
        int i = (bi - 1569) * 256 + t;        // 0..6143
        if (i < 4096) {                       // w3f[kb][n][j] = fo0[kb*8+j][n]*s3[n], pad k>=48
            int j = i & 7, n = (i >> 3) & 63, kb = i >> 9;
            int k = kb * 8 + j;
            float s3 = g3[n] * rsqrtf(v3[n] + 1e-3f);
            w3f[i] = (k < 48) ? (_Float16)(w3[k * 64 + n] * s3) : (_Float16)0.f;
        } else {                              // w4f: sigma-permuted, s4-scaled
            int i2 = i - 4096;
            int j = i2 & 7, n = (i2 >> 3) & 31, kb = i2 >> 8;
            int ks = kb >> 2, g = kb & 3;
            int src = (2 * ks + (j >> 2)) * 16 + 4 * g + (j & 3);
            float s4 = g4[n] * rsqrtf(v4[n] + 1e-3f);
            w3f[4096 + i2] = (_Float16)(w4[src * 32 + n] * s4);
        }
    } else {
        int n = (bi - 1593) * 256 + t;        // 0..8191 nodes
        int b = n >> 7, pn = n & 127;
        _Float16 tmp[16];
#pragma unroll
        for (int f = 0; f < NF; ++f) tmp[f] = (_Float16)x[(b * NF + f) * NP + pn];
        *(f16x8*)&xt16[n * 16]     = *(f16x8*)&tmp[0];
        *(f16x8*)&xt16[n * 16 + 8] = *(f16x8*)&tmp[8];
    }
}

// ---------------- edge MLP + per-block fo ----------------
// Grid: 4096 blocks, 256 threads = 4 waves. Block = (b, 2 receivers).
// Wave w: receiver rb = w>>1, edge-half h = w&1 (64 edges = 2 chunks of 32).
__global__ __launch_bounds__(256) void edge_fused(
    const _Float16* __restrict__ Rch, const _Float16* __restrict__ Sc2,
    const _Float16* __restrict__ w1f,      // w1f(6144) || w2f(2048)
    const _Float16* __restrict__ w3f,      // w3f(4096) || w4f(2048)
    const _Float16* __restrict__ c1h, const _Float16* __restrict__ c3h,
    const float* __restrict__ cs, const _Float16* __restrict__ xt16,
    float* __restrict__ fo_out)
{
    __shared__ _Float16 bw2L[2048];    // fr2 weight frags (4 KB)
    __shared__ float    psum[4][32];
    __shared__ _Float16 Hl[16][72];    // rows 0..1 valid

    const int tid  = threadIdx.x;
    const int w    = tid >> 6;
    const int lane = tid & 63;
    const int g    = lane >> 4;
    const int l15  = lane & 15;
    const int blk  = blockIdx.x;
    const int b    = blk >> 6;
    const int pbase = (blk & 63) * 2;
    const int rb   = w >> 1;
    const int h    = w & 1;
    const int p    = pbase + rb;

    // stage fr2 weights to LDS (one uint4 per thread)
    ((uint4*)bw2L)[tid] = ((const uint4*)(w1f + 6144))[tid];
    __syncthreads();

    // ---- fr1 weights + per-lane consts in registers ----
    f16x8 bw1[3][4];
#pragma unroll
    for (int ks = 0; ks < 3; ++ks)
#pragma unroll
        for (int mt = 0; mt < 4; ++mt)
            bw1[ks][mt] = *(const f16x8*)&w1f[(((ks * 4 + g) * 64) + mt * 16 + l15) * 8];
    f16x8 rc[3];
#pragma unroll
    for (int ks = 0; ks < 3; ++ks)
        rc[ks] = *(const f16x8*)&Rch[(size_t)(b * NP + p) * 96 + ks * 32 + g * 8];
    f16x2 c1pk[4][2];
#pragma unroll
    for (int mt = 0; mt < 4; ++mt)
#pragma unroll
        for (int rp = 0; rp < 2; ++rp)
            c1pk[mt][rp] = *(const f16x2*)&c1h[mt * 16 + 4 * g + 2 * rp];
    f32x4 c2v[2];
#pragma unroll
    for (int mt = 0; mt < 2; ++mt)
        c2v[mt] = *(const f32x4*)&cs[352 + mt * 16 + 4 * g];

    f32x4 sums[2];
    sums[0] = (f32x4){0.f, 0.f, 0.f, 0.f};
    sums[1] = (f32x4){0.f, 0.f, 0.f, 0.f};

#pragma unroll
    for (int c = 0; c < 2; ++c) {
#pragma unroll
        for (int nt = 0; nt < 2; ++nt) {
            const int row = h * 64 + c * 32 + nt * 16 + l15;   // edge index
            // ---- E1^T B-frag from coalesced k-planes ----
            f16x8 bf[3];
#pragma unroll
            for (int ks = 0; ks < 3; ++ks) {
                f16x8 sv = *(const f16x8*)&Sc2[(size_t)((b * 3 + ks) * NP + row) * 32 + g * 8];
                f16x8 tv = sv + rc[ks];
                f16x8 zz = {};
                bf[ks] = __builtin_elementwise_max(tv, zz);
            }
            // ---- fr1: 12 MFMAs into acc[4] ----
            f32x4 acc[4];
#pragma unroll
            for (int mt = 0; mt < 4; ++mt) acc[mt] = (f32x4){0.f, 0.f, 0.f, 0.f};
#pragma unroll
            for (int ks = 0; ks < 3; ++ks)
#pragma unroll
                for (int mt = 0; mt < 4; ++mt)
                    acc[mt] = __builtin_amdgcn_mfma_f32_16x16x32_f16(bw1[ks][mt], bf[ks], acc[mt], 0, 0, 0);
            // ---- epilogue 1 (packed fp16) ----
            f16x2 pw[4][2];
#pragma unroll
            for (int mt = 0; mt < 4; ++mt)
#pragma unroll
                for (int rp = 0; rp < 2; ++rp) {
                    f16x2 hh = cvt_pk(acc[mt][2 * rp], acc[mt][2 * rp + 1]);
                    hh = hh + c1pk[mt][rp];
                    f16x2 zz = {};
                    pw[mt][rp] = __builtin_elementwise_max(hh, zz);
                }
            // ---- fr2 via sigma handoff (bit_cast pack, weights from LDS) ----
            f32x4 acc2[2];
            acc2[0] = (f32x4){0.f, 0.f, 0.f, 0.f};
            acc2[1] = (f32x4){0.f, 0.f, 0.f, 0.f};
#pragma unroll
            for (int ks = 0; ks < 2; ++ks) {
                uint4 uu;
                uu.x = bc32(pw[2 * ks][0]);
                uu.y = bc32(pw[2 * ks][1]);
                uu.z = bc32(pw[2 * ks + 1][0]);
                uu.w = bc32(pw[2 * ks + 1][1]);
                f16x8 u = __builtin_bit_cast(f16x8, uu);
#pragma unroll
                for (int mt = 0; mt < 2; ++mt) {
                    f16x8 a2 = *(const f16x8*)&bw2L[(((ks * 4 + g) * 32) + mt * 16 + l15) * 8];
                    acc2[mt] = __builtin_amdgcn_mfma_f32_16x16x32_f16(a2, u, acc2[mt], 0, 0, 0);
                }
            }
            // ---- epilogue 2: relu(C2 + c2), accumulate senders != p ----
#pragma unroll
            for (int mt = 0; mt < 2; ++mt)
#pragma unroll
                for (int r = 0; r < 4; ++r) {
                    float v = fmaxf(acc2[mt][r] + c2v[mt][r], 0.f);
                    sums[mt][r] += (row != p) ? v : 0.f;
                }
        }
    }

    // ---- reduce over the 16 edge-lanes within each group ----
#pragma unroll
    for (int mt = 0; mt < 2; ++mt)
#pragma unroll
        for (int d = 1; d <= 8; d <<= 1) {
            sums[mt][0] += __shfl_xor(sums[mt][0], d, 64);
            sums[mt][1] += __shfl_xor(sums[mt][1], d, 64);
            sums[mt][2] += __shfl_xor(sums[mt][2], d, 64);
            sums[mt][3] += __shfl_xor(sums[mt][3], d, 64);
        }
    if (l15 == 0) {
#pragma unroll
        for (int mt = 0; mt < 2; ++mt)
            *(f32x4*)&psum[w][mt * 16 + 4 * g] = sums[mt];
    }
    __syncthreads();

    // ---- merge wave pairs, build H rows for the block's 2 receivers ----
    if (tid < 64) {
        int r = tid >> 5, ch = tid & 31;
        Hl[r][16 + ch] = (_Float16)(psum[2 * r][ch] + psum[2 * r + 1][ch]);
    } else if (tid < 96) {
        int i = tid - 64, r = i >> 4, f = i & 15;
        Hl[r][f] = xt16[(size_t)(b * NP + pbase + r) * 16 + f];
    } else if (tid < 128) {
        int i = tid - 96, r = i >> 4;
        Hl[r][48 + (i & 15)] = (_Float16)0.f;
    }
    __syncthreads();

    // ---- fo MLP on wave 0 (nodes on l15; cols >=2 are garbage, unstored) ----
    if (w == 0) {
        f16x8 bfo[2];
#pragma unroll
        for (int ks = 0; ks < 2; ++ks)
            bfo[ks] = *(const f16x8*)&Hl[l15][ks * 32 + g * 8];
        f32x4 acc3[4];
#pragma unroll
        for (int mt = 0; mt < 4; ++mt) acc3[mt] = (f32x4){0.f, 0.f, 0.f, 0.f};
#pragma unroll
        for (int ks = 0; ks < 2; ++ks)
#pragma unroll
            for (int mt = 0; mt < 4; ++mt) {
                f16x8 a3 = *(const f16x8*)&w3f[(((ks * 4 + g) * 64) + mt * 16 + l15) * 8];
                acc3[mt] = __builtin_amdgcn_mfma_f32_16x16x32_f16(a3, bfo[ks], acc3[mt], 0, 0, 0);
            }
        f16x2 pw3[4][2];
#pragma unroll
        for (int mt = 0; mt < 4; ++mt)
#pragma unroll
            for (int rp = 0; rp < 2; ++rp) {
                f16x2 hh = cvt_pk(acc3[mt][2 * rp], acc3[mt][2 * rp + 1]);
                hh = hh + *(const f16x2*)&c3h[mt * 16 + 4 * g + 2 * rp];
                f16x2 zz = {};
                pw3[mt][rp] = __builtin_elementwise_max(hh, zz);
            }
        f32x4 acc4[2];
        acc4[0] = (f32x4){0.f, 0.f, 0.f, 0.f};
        acc4[1] = (f32x4){0.f, 0.f, 0.f, 0.f};
#pragma unroll
        for (int ks = 0; ks < 2; ++ks) {
            uint4 uu;
            uu.x = bc32(pw3[2 * ks][0]);
            uu.y = bc32(pw3[2 * ks][1]);
            uu.z = bc32(pw3[2 * ks + 1][0]);
            uu.w = bc32(pw3[2 * ks + 1][1]);
            f16x8 u = __builtin_bit_cast(f16x8, uu);
#pragma unroll
            for (int mt = 0; mt < 2; ++mt) {
                f16x8 a4 = *(const f16x8*)&w3f[4096 + (((ks * 4 + g) * 32) + mt * 16 + l15) * 8];
                acc4[mt] = __builtin_amdgcn_mfma_f32_16x16x32_f16(a4, u, acc4[mt], 0, 0, 0);
            }
        }
        if (l15 < 2) {
#pragma unroll
            for (int mt = 0; mt < 2; ++mt) {
                f32x4 c4 = *(const f32x4*)&cs[512 + mt * 16 + 4 * g];
                f32x4 o;
#pragma unroll
                for (int r = 0; r < 4; ++r) o[r] = fmaxf(acc4[mt][r] + c4[r], 0.f);
                *(f32x4*)&fo_out[(size_t)(b * NP + pbase + l15) * 32 + mt * 16 + 4 * g] = o;
            }
        }
    }
}

// ---------------- deterministic sum over nodes ----------------
__global__ void reduce_kernel(const float* __restrict__ fo_out, float* __restrict__ out) {
    int b = blockIdx.x;              // 64 blocks
    int t = threadIdx.x;             // 256
    int m = t & 31;
    int g = t >> 5;                  // 8 groups
    float v = 0.f;
    for (int p = g; p < NP; p += 8) v += fo_out[(b * NP + p) * 32 + m];
    __shared__ float red[256];
    red[t] = v;
    __syncthreads();
    for (int s = 4; s >= 1; s >>= 1) {
        if (g < s) red[t] += red[t + s * 32];
        __syncthreads();
    }
    if (g == 0) out[b * 32 + m] = red[t];
}

extern "C" void kernel_launch(void* const* d_in, const int* in_sizes, int n_in,
                              void* d_out, int out_size, void* d_ws, size_t ws_size,
                              hipStream_t stream) {
    (void)in_sizes; (void)n_in; (void)out_size; (void)ws_size;
    const float* x    = (const float*)d_in[0];
    const float* fr0w = (const float*)d_in[1];
    const float* fr1w = (const float*)d_in[7];
    const float* fr2w = (const float*)d_in[13];
    const float* fo0w = (const float*)d_in[19];
    const float* fo1w = (const float*)d_in[25];

    float* ws = (float*)d_ws;
    float*    cs     = ws;                                   // 1024 f32
    _Float16* Rch    = (_Float16*)(ws + 1024);               // 786432 f16
    _Float16* Sc2    = (_Float16*)(ws + 394240);             // 786432 f16
    _Float16* w1f    = (_Float16*)(ws + 787456);             // 8192 f16 (w1f||w2f)
    _Float16* w3f    = (_Float16*)(ws + 791552);             // 6144 f16 (w3f||w4f)
    _Float16* c1h    = (_Float16*)(ws + 794624);             // 64 f16
    _Float16* c3h    = c1h + 64;                             // 64 f16
    _Float16* xt16   = (_Float16*)(ws + 794688);             // 131072 f16
    float*    fo_out = ws + 860224;                          // B*P*32 f32
    float*    out    = (float*)d_out;

    prep_kernel<<<1625, 256, 0, stream>>>(x, fr0w, fr1w, fr2w, fo0w, fo1w,
        w1f, w3f, cs, c1h, c3h, xt16, Rch, Sc2,
        (const float*)d_in[2],  (const float*)d_in[3],  (const float*)d_in[4],
        (const float*)d_in[5],  (const float*)d_in[6],
        (const float*)d_in[8],  (const float*)d_in[9],  (const float*)d_in[10],
        (const float*)d_in[11], (const float*)d_in[12],
        (const float*)d_in[14], (const float*)d_in[15], (const float*)d_in[16],
        (const float*)d_in[17], (const float*)d_in[18],
        (const float*)d_in[20], (const float*)d_in[21], (const float*)d_in[22],
        (const float*)d_in[23], (const float*)d_in[24],
        (const float*)d_in[26], (const float*)d_in[27], (const float*)d_in[28],
        (const float*)d_in[29], (const float*)d_in[30]);

    edge_fused<<<NB * 64, 256, 0, stream>>>(Rch, Sc2, w1f, w3f, c1h, c3h, cs, xt16, fo_out);

    reduce_kernel<<<NB, 256, 0, stream>>>(fo_out, out);
}

// Round 9
// 53.520 us; speedup vs baseline: 1.3870x; 1.0449x over previous
//
#include <hip/hip_runtime.h>

// GraphEmbeddings interaction network — swapped-operand MFMA, sigma in-register
// fr1->fr2 handoff, nt-streamed, bw2 via LDS, 2 waves/receiver, NO fo tail:
// edge waves write partial sums to aggh[node][2][32]; a separate MFMA fo
// kernel (16 nodes/wave) consumes them. Edge waves exit independently.

#define NB 64
#define NF 16
#define NP 128

typedef _Float16 f16x8 __attribute__((ext_vector_type(8)));
typedef _Float16 f16x2 __attribute__((ext_vector_type(2)));
typedef float    f32x4 __attribute__((ext_vector_type(4)));

__device__ __forceinline__ f16x2 cvt_pk(float a, float b) {
    return __builtin_bit_cast(f16x2, __builtin_amdgcn_cvt_pkrtz(a, b));
}
__device__ __forceinline__ unsigned bc32(f16x2 h) {
    return __builtin_bit_cast(unsigned, h);
}

// ---------------- prep ----------------
__global__ void prep_kernel(const float* __restrict__ x, const float* __restrict__ w0,
                            const float* __restrict__ w1, const float* __restrict__ w2,
                            const float* __restrict__ w3, const float* __restrict__ w4,
                            _Float16* __restrict__ w1f, _Float16* __restrict__ w3f,
                            float* __restrict__ cs, _Float16* __restrict__ c1h,
                            _Float16* __restrict__ c3h, _Float16* __restrict__ xt16,
                            _Float16* __restrict__ Rch, _Float16* __restrict__ Sc2,
    const float* b0, const float* g0, const float* be0, const float* m0, const float* v0,
    const float* b1, const float* g1, const float* be1, const float* m1, const float* v1,
    const float* b2, const float* g2, const float* be2, const float* m2, const float* v2,
    const float* b3, const float* g3, const float* be3, const float* m3, const float* v3,
    const float* b4, const float* g4, const float* be4, const float* m4, const float* v4)
{
    const int bi = blockIdx.x;
    const int t = threadIdx.x;
    if (bi < 1536) {
        int idx = bi * 256 + t;            // B*P*48 (2 ch per thread)
        int c2i = idx % 48;
        int node = idx / 48;
        int p = node & (NP - 1);
        int b = node >> 7;
        int ch0 = c2i * 2, ch1 = ch0 + 1;
        float sa = g0[ch0] * rsqrtf(v0[ch0] + 1e-3f);
        float sb = g0[ch1] * rsqrtf(v0[ch1] + 1e-3f);
        float ca = (b0[ch0] - m0[ch0]) * sa + be0[ch0];
        float cb = (b0[ch1] - m0[ch1]) * sb + be0[ch1];
        const float* xb = x + b * NF * NP + p;
        float r0 = 0.f, r1 = 0.f, s0 = 0.f, s1 = 0.f;
#pragma unroll
        for (int f = 0; f < NF; ++f) {
            float xv = xb[f * NP];
            float2 wr = *(const float2*)&w0[f * 96 + ch0];
            float2 ws = *(const float2*)&w0[(NF + f) * 96 + ch0];
            r0 += xv * wr.x; r1 += xv * wr.y;
            s0 += xv * ws.x; s1 += xv * ws.y;
        }
        f16x2 rv; rv[0] = (_Float16)(r0 * sa + ca); rv[1] = (_Float16)(r1 * sb + cb);
        f16x2 sv; sv[0] = (_Float16)(s0 * sa);      sv[1] = (_Float16)(s1 * sb);
        *(f16x2*)&Rch[node * 96 + ch0] = rv;
        int ks = ch0 >> 5;                 // plane (pair stays within one plane)
        *(f16x2*)&Sc2[((b * 3 + ks) * NP + p) * 32 + (ch0 - ks * 32)] = sv;
    } else if (bi == 1536) {
        if (t < 64) {
            float s = g1[t] * rsqrtf(v1[t] + 1e-3f);
            c1h[t] = (_Float16)((b1[t] - m1[t]) * s + be1[t]);
        }
        if (t < 32) {
            float s = g2[t] * rsqrtf(v2[t] + 1e-3f);
            cs[352 + t] = (b2[t] - m2[t]) * s + be2[t];
        }
        if (t < 64) {
            float s = g3[t] * rsqrtf(v3[t] + 1e-3f);
            c3h[t] = (_Float16)((b3[t] - m3[t]) * s + be3[t]);
        }
        if (t < 32) {
            float s = g4[t] * rsqrtf(v4[t] + 1e-3f);
            cs[512 + t] = (b4[t] - m4[t]) * s + be4[t];
        }
    } else if (bi < 1569) {
        int i = (bi - 1537) * 256 + t;        // 0..8191
        if (i < 6144) {                       // w1f[kb][n][j] = W1[kb*8+j][n]*s1[n]
            int j = i & 7, n = (i >> 3) & 63, kb = i >> 9;
            float s1 = g1[n] * rsqrtf(v1[n] + 1e-3f);
            w1f[i] = (_Float16)(w1[(kb * 8 + j) * 64 + n] * s1);
        } else {                              // w2f: sigma-permuted K, s2-scaled
            int i2 = i - 6144;
            int j = i2 & 7, n = (i2 >> 3) & 31, kb = i2 >> 8;
            int ks = kb >> 2, g = kb & 3;
            int src = (2 * ks + (j >> 2)) * 16 + 4 * g + (j & 3);
            float s2 = g2[n] * rsqrtf(v2[n] + 1e-3f);
            w1f[6144 + i2] = (_Float16)(w2[src * 32 + n] * s2);
        }
    } else if (bi < 1593) {
        int i = (bi - 1569) * 256 + t;        // 0..6143
        if (i < 4096) {                       // w3f[kb][n][j] = fo0[kb*8+j][n]*s3[n], pad k>=48
            int j = i & 7, n = (i >> 3) & 63, kb = i >> 9;
            int k = kb * 8 + j;
            float s3 = g3[n] * rsqrtf(v3[n] + 1e-3f);
            w3f[i] = (k < 48) ? (_Float16)(w3[k * 64 + n] * s3) : (_Float16)0.f;
        } else {                              // w4f: sigma-permuted, s4-scaled
            int i2 = i - 4096;
            int j = i2 & 7, n = (i2 >> 3) & 31, kb = i2 >> 8;
            int ks = kb >> 2, g = kb & 3;
            int src = (2 * ks + (j >> 2)) * 16 + 4 * g + (j & 3);
            float s4 = g4[n] * rsqrtf(v4[n] + 1e-3f);
            w3f[4096 + i2] = (_Float16)(w4[src * 32 + n] * s4);
        }
    } else {
        int n = (bi - 1593) * 256 + t;        // 0..8191 nodes
        int b = n >> 7, pn = n & 127;
        _Float16 tmp[16];
#pragma unroll
        for (int f = 0; f < NF; ++f) tmp[f] = (_Float16)x[(b * NF + f) * NP + pn];
        *(f16x8*)&xt16[n * 16]     = *(f16x8*)&tmp[0];
        *(f16x8*)&xt16[n * 16 + 8] = *(f16x8*)&tmp[8];
    }
}

// ---------------- edge MLP: partial sums only, no tail ----------------
// Grid: 4096 blocks, 256 threads = 4 waves. Block = (b, 2 receivers).
// Wave w: receiver rb = w>>1, edge-half h = w&1 (64 edges = 2 chunks of 32).
__global__ __launch_bounds__(256) void edge_kernel(
    const _Float16* __restrict__ Rch, const _Float16* __restrict__ Sc2,
    const _Float16* __restrict__ w1f,      // w1f(6144) || w2f(2048)
    const _Float16* __restrict__ c1h, const float* __restrict__ cs,
    float* __restrict__ aggh)              // [node][2][32] f32
{
    __shared__ _Float16 bw2L[2048];    // fr2 weight frags (4 KB)

    const int tid  = threadIdx.x;
    const int w    = tid >> 6;
    const int lane = tid & 63;
    const int g    = lane >> 4;
    const int l15  = lane & 15;
    const int blk  = blockIdx.x;
    const int b    = blk >> 6;
    const int pbase = (blk & 63) * 2;
    const int rb   = w >> 1;
    const int h    = w & 1;
    const int p    = pbase + rb;

    // stage fr2 weights to LDS (one uint4 per thread)
    ((uint4*)bw2L)[tid] = ((const uint4*)(w1f + 6144))[tid];
    __syncthreads();

    // ---- fr1 weights + per-lane consts in registers ----
    f16x8 bw1[3][4];
#pragma unroll
    for (int ks = 0; ks < 3; ++ks)
#pragma unroll
        for (int mt = 0; mt < 4; ++mt)
            bw1[ks][mt] = *(const f16x8*)&w1f[(((ks * 4 + g) * 64) + mt * 16 + l15) * 8];
    f16x8 rc[3];
#pragma unroll
    for (int ks = 0; ks < 3; ++ks)
        rc[ks] = *(const f16x8*)&Rch[(size_t)(b * NP + p) * 96 + ks * 32 + g * 8];
    f16x2 c1pk[4][2];
#pragma unroll
    for (int mt = 0; mt < 4; ++mt)
#pragma unroll
        for (int rp = 0; rp < 2; ++rp)
            c1pk[mt][rp] = *(const f16x2*)&c1h[mt * 16 + 4 * g + 2 * rp];
    f32x4 c2v[2];
#pragma unroll
    for (int mt = 0; mt < 2; ++mt)
        c2v[mt] = *(const f32x4*)&cs[352 + mt * 16 + 4 * g];

    f32x4 sums[2];
    sums[0] = (f32x4){0.f, 0.f, 0.f, 0.f};
    sums[1] = (f32x4){0.f, 0.f, 0.f, 0.f};

#pragma unroll
    for (int c = 0; c < 2; ++c) {
#pragma unroll
        for (int nt = 0; nt < 2; ++nt) {
            const int row = h * 64 + c * 32 + nt * 16 + l15;   // edge index
            // ---- E1^T B-frag from coalesced k-planes ----
            f16x8 bf[3];
#pragma unroll
            for (int ks = 0; ks < 3; ++ks) {
                f16x8 sv = *(const f16x8*)&Sc2[(size_t)((b * 3 + ks) * NP + row) * 32 + g * 8];
                f16x8 tv = sv + rc[ks];
                f16x8 zz = {};
                bf[ks] = __builtin_elementwise_max(tv, zz);
            }
            // ---- fr1: 12 MFMAs into acc[4] ----
            f32x4 acc[4];
#pragma unroll
            for (int mt = 0; mt < 4; ++mt) acc[mt] = (f32x4){0.f, 0.f, 0.f, 0.f};
#pragma unroll
            for (int ks = 0; ks < 3; ++ks)
#pragma unroll
                for (int mt = 0; mt < 4; ++mt)
                    acc[mt] = __builtin_amdgcn_mfma_f32_16x16x32_f16(bw1[ks][mt], bf[ks], acc[mt], 0, 0, 0);
            // ---- epilogue 1 (packed fp16) ----
            f16x2 pw[4][2];
#pragma unroll
            for (int mt = 0; mt < 4; ++mt)
#pragma unroll
                for (int rp = 0; rp < 2; ++rp) {
                    f16x2 hh = cvt_pk(acc[mt][2 * rp], acc[mt][2 * rp + 1]);
                    hh = hh + c1pk[mt][rp];
                    f16x2 zz = {};
                    pw[mt][rp] = __builtin_elementwise_max(hh, zz);
                }
            // ---- fr2 via sigma handoff (weights from LDS) ----
            f32x4 acc2[2];
            acc2[0] = (f32x4){0.f, 0.f, 0.f, 0.f};
            acc2[1] = (f32x4){0.f, 0.f, 0.f, 0.f};
#pragma unroll
            for (int ks = 0; ks < 2; ++ks) {
                uint4 uu;
                uu.x = bc32(pw[2 * ks][0]);
                uu.y = bc32(pw[2 * ks][1]);
                uu.z = bc32(pw[2 * ks + 1][0]);
                uu.w = bc32(pw[2 * ks + 1][1]);
                f16x8 u = __builtin_bit_cast(f16x8, uu);
#pragma unroll
                for (int mt = 0; mt < 2; ++mt) {
                    f16x8 a2 = *(const f16x8*)&bw2L[(((ks * 4 + g) * 32) + mt * 16 + l15) * 8];
                    acc2[mt] = __builtin_amdgcn_mfma_f32_16x16x32_f16(a2, u, acc2[mt], 0, 0, 0);
                }
            }
            // ---- epilogue 2: relu(C2 + c2), accumulate senders != p ----
#pragma unroll
            for (int mt = 0; mt < 2; ++mt)
#pragma unroll
                for (int r = 0; r < 4; ++r) {
                    float v = fmaxf(acc2[mt][r] + c2v[mt][r], 0.f);
                    sums[mt][r] += (row != p) ? v : 0.f;
                }
        }
    }

    // ---- reduce over the 16 edge-lanes within each group; store partials ----
#pragma unroll
    for (int mt = 0; mt < 2; ++mt)
#pragma unroll
        for (int d = 1; d <= 8; d <<= 1) {
            sums[mt][0] += __shfl_xor(sums[mt][0], d, 64);
            sums[mt][1] += __shfl_xor(sums[mt][1], d, 64);
            sums[mt][2] += __shfl_xor(sums[mt][2], d, 64);
            sums[mt][3] += __shfl_xor(sums[mt][3], d, 64);
        }
    if (l15 == 0) {
#pragma unroll
        for (int mt = 0; mt < 2; ++mt)
            *(f32x4*)&aggh[(size_t)((b * NP + p) * 2 + h) * 32 + mt * 16 + 4 * g] = sums[mt];
    }
}

// ---------------- fo MLP via MFMA: 16 nodes per wave ----------------
// Grid: 128 blocks x 256 thr = 512 waves; wave wv handles nodes wv*16+l15.
__global__ __launch_bounds__(256) void fo_kernel(
    const float* __restrict__ aggh, const _Float16* __restrict__ xt16,
    const _Float16* __restrict__ w3f,      // w3f(4096) || w4f(2048)
    const _Float16* __restrict__ c3h, const float* __restrict__ cs,
    float* __restrict__ fo_out)
{
    const int tid  = threadIdx.x;
    const int lane = tid & 63;
    const int g    = lane >> 4;
    const int l15  = lane & 15;
    const int wv   = blockIdx.x * 4 + (tid >> 6);
    const int node = wv * 16 + l15;

    // ---- build B-frags of H^T: cols 0..15 = x, 16..47 = agg sum, 48..63 = 0
    f16x8 bfo[2];
    if (g < 2) {
        bfo[0] = *(const f16x8*)&xt16[(size_t)node * 16 + g * 8];
        int c0 = 16 + g * 8;           // agg cols 0..15
        const float* a0 = &aggh[(size_t)node * 64 + (c0 - 16)];
        f16x8 t;
#pragma unroll
        for (int j = 0; j < 8; ++j) t[j] = (_Float16)(a0[j] + a0[32 + j]);
        bfo[1] = t;
    } else {
        int c0 = (g - 2) * 8 + 16;     // agg cols 16..31
        const float* a0 = &aggh[(size_t)node * 64 + (c0 - 16) + 8]; // cols (g-2)*8+... 
        // careful: ks=0, k=g*8 => agg col g*8-16 (g=2->0..7, g=3->8..15)
        const float* b0 = &aggh[(size_t)node * 64 + (g - 2) * 8];
        f16x8 t;
#pragma unroll
        for (int j = 0; j < 8; ++j) t[j] = (_Float16)(b0[j] + b0[32 + j]);
        bfo[0] = t;
        f16x8 zz = {};
        bfo[1] = zz;
        (void)a0; (void)c0;
    }
    // fix bfo[1] for g<2 handled above; for g>=2 zero. For g<2, bfo[1] covers k=32+g*8
    if (g < 2) {
        const float* b1 = &aggh[(size_t)node * 64 + 16 + g * 8];   // agg cols 16..31
        f16x8 t;
#pragma unroll
        for (int j = 0; j < 8; ++j) t[j] = (_Float16)(b1[j] + b1[32 + j]);
        bfo[1] = t;
    }

    // ---- fo0: C3^T = W3^T x H^T ----
    f32x4 acc3[4];
#pragma unroll
    for (int mt = 0; mt < 4; ++mt) acc3[mt] = (f32x4){0.f, 0.f, 0.f, 0.f};
#pragma unroll
    for (int ks = 0; ks < 2; ++ks)
#pragma unroll
        for (int mt = 0; mt < 4; ++mt) {
            f16x8 a3 = *(const f16x8*)&w3f[(((ks * 4 + g) * 64) + mt * 16 + l15) * 8];
            acc3[mt] = __builtin_amdgcn_mfma_f32_16x16x32_f16(a3, bfo[ks], acc3[mt], 0, 0, 0);
        }
    f16x2 pw3[4][2];
#pragma unroll
    for (int mt = 0; mt < 4; ++mt)
#pragma unroll
        for (int rp = 0; rp < 2; ++rp) {
            f16x2 hh = cvt_pk(acc3[mt][2 * rp], acc3[mt][2 * rp + 1]);
            hh = hh + *(const f16x2*)&c3h[mt * 16 + 4 * g + 2 * rp];
            f16x2 zz = {};
            pw3[mt][rp] = __builtin_elementwise_max(hh, zz);
        }
    // ---- fo1 via sigma handoff ----
    f32x4 acc4[2];
    acc4[0] = (f32x4){0.f, 0.f, 0.f, 0.f};
    acc4[1] = (f32x4){0.f, 0.f, 0.f, 0.f};
#pragma unroll
    for (int ks = 0; ks < 2; ++ks) {
        uint4 uu;
        uu.x = bc32(pw3[2 * ks][0]);
        uu.y = bc32(pw3[2 * ks][1]);
        uu.z = bc32(pw3[2 * ks + 1][0]);
        uu.w = bc32(pw3[2 * ks + 1][1]);
        f16x8 u = __builtin_bit_cast(f16x8, uu);
#pragma unroll
        for (int mt = 0; mt < 2; ++mt) {
            f16x8 a4 = *(const f16x8*)&w3f[4096 + (((ks * 4 + g) * 32) + mt * 16 + l15) * 8];
            acc4[mt] = __builtin_amdgcn_mfma_f32_16x16x32_f16(a4, u, acc4[mt], 0, 0, 0);
        }
    }
#pragma unroll
    for (int mt = 0; mt < 2; ++mt) {
        f32x4 c4 = *(const f32x4*)&cs[512 + mt * 16 + 4 * g];
        f32x4 o;
#pragma unroll
        for (int r = 0; r < 4; ++r) o[r] = fmaxf(acc4[mt][r] + c4[r], 0.f);
        *(f32x4*)&fo_out[(size_t)node * 32 + mt * 16 + 4 * g] = o;
    }
}

// ---------------- deterministic sum over nodes ----------------
__global__ void reduce_kernel(const float* __restrict__ fo_out, float* __restrict__ out) {
    int b = blockIdx.x;              // 64 blocks
    int t = threadIdx.x;             // 256
    int m = t & 31;
    int g = t >> 5;                  // 8 groups
    float v = 0.f;
    for (int p = g; p < NP; p += 8) v += fo_out[(b * NP + p) * 32 + m];
    __shared__ float red[256];
    red[t] = v;
    __syncthreads();
    for (int s = 4; s >= 1; s >>= 1) {
        if (g < s) red[t] += red[t + s * 32];
        __syncthreads();
    }
    if (g == 0) out[b * 32 + m] = red[t];
}

extern "C" void kernel_launch(void* const* d_in, const int* in_sizes, int n_in,
                              void* d_out, int out_size, void* d_ws, size_t ws_size,
                              hipStream_t stream) {
    (void)in_sizes; (void)n_in; (void)out_size; (void)ws_size;
    const float* x    = (const float*)d_in[0];
    const float* fr0w = (const float*)d_in[1];
    const float* fr1w = (const float*)d_in[7];
    const float* fr2w = (const float*)d_in[13];
    const float* fo0w = (const float*)d_in[19];
    const float* fo1w = (const float*)d_in[25];

    float* ws = (float*)d_ws;
    float*    cs     = ws;                                   // 1024 f32
    _Float16* Rch    = (_Float16*)(ws + 1024);               // 786432 f16
    _Float16* Sc2    = (_Float16*)(ws + 394240);             // 786432 f16
    _Float16* w1f    = (_Float16*)(ws + 787456);             // 8192 f16 (w1f||w2f)
    _Float16* w3f    = (_Float16*)(ws + 791552);             // 6144 f16 (w3f||w4f)
    _Float16* c1h    = (_Float16*)(ws + 794624);             // 64 f16
    _Float16* c3h    = c1h + 64;                             // 64 f16
    _Float16* xt16   = (_Float16*)(ws + 794688);             // 131072 f16
    float*    aggh   = ws + 860224;                          // 8192*64 f32
    float*    fo_out = ws + 1384512;                         // B*P*32 f32
    float*    out    = (float*)d_out;

    prep_kernel<<<1625, 256, 0, stream>>>(x, fr0w, fr1w, fr2w, fo0w, fo1w,
        w1f, w3f, cs, c1h, c3h, xt16, Rch, Sc2,
        (const float*)d_in[2],  (const float*)d_in[3],  (const float*)d_in[4],
        (const float*)d_in[5],  (const float*)d_in[6],
        (const float*)d_in[8],  (const float*)d_in[9],  (const float*)d_in[10],
        (const float*)d_in[11], (const float*)d_in[12],
        (const float*)d_in[14], (const float*)d_in[15], (const float*)d_in[16],
        (const float*)d_in[17], (const float*)d_in[18],
        (const float*)d_in[20], (const float*)d_in[21], (const float*)d_in[22],
        (const float*)d_in[23], (const float*)d_in[24],
        (const float*)d_in[26], (const float*)d_in[27], (const float*)d_in[28],
        (const float*)d_in[29], (const float*)d_in[30]);

    edge_kernel<<<NB * 64, 256, 0, stream>>>(Rch, Sc2, w1f, c1h, cs, aggh);

    fo_kernel<<<128, 256, 0, stream>>>(aggh, xt16, w3f, c3h, cs, fo_out);

    reduce_kernel<<<NB, 256, 0, stream>>>(fo_out, out);
}

// Round 10
// 43.360 us; speedup vs baseline: 1.7120x; 1.2343x over previous
//
#include <hip/hip_runtime.h>

// GraphEmbeddings interaction network — swapped-operand MFMA, sigma in-register
// fr1->fr2 handoff. R10: one wave = one receiver's FULL 128 edges (8 iters),
// aggh single partial per node; fo+reduce fused per-batch block. 3 launches.

#define NB 64
#define NF 16
#define NP 128

typedef _Float16 f16x8 __attribute__((ext_vector_type(8)));
typedef _Float16 f16x2 __attribute__((ext_vector_type(2)));
typedef float    f32x4 __attribute__((ext_vector_type(4)));

__device__ __forceinline__ f16x2 cvt_pk(float a, float b) {
    return __builtin_bit_cast(f16x2, __builtin_amdgcn_cvt_pkrtz(a, b));
}
__device__ __forceinline__ unsigned bc32(f16x2 h) {
    return __builtin_bit_cast(unsigned, h);
}

// ---------------- prep ----------------
// blocks 0..1535   : Rc ([node][96]) and Sc2 (k-planes [(b*3+ks)*128+a][32]), fp16
// block 1536       : consts c1h, c2 (cs+352), c3h, c4 (cs+512)
// blocks 1537..1568: w1f (W1^T s1-scaled frags) + w2f (sigma, s2-scaled)
// blocks 1569..1592: w3f (fo0^T s3-scaled, K 48->64 zero-pad) + w4f (sigma, s4)
// blocks 1593..1624: xt16[node][16] transpose of x
__global__ void prep_kernel(const float* __restrict__ x, const float* __restrict__ w0,
                            const float* __restrict__ w1, const float* __restrict__ w2,
                            const float* __restrict__ w3, const float* __restrict__ w4,
                            _Float16* __restrict__ w1f, _Float16* __restrict__ w3f,
                            float* __restrict__ cs, _Float16* __restrict__ c1h,
                            _Float16* __restrict__ c3h, _Float16* __restrict__ xt16,
                            _Float16* __restrict__ Rch, _Float16* __restrict__ Sc2,
    const float* b0, const float* g0, const float* be0, const float* m0, const float* v0,
    const float* b1, const float* g1, const float* be1, const float* m1, const float* v1,
    const float* b2, const float* g2, const float* be2, const float* m2, const float* v2,
    const float* b3, const float* g3, const float* be3, const float* m3, const float* v3,
    const float* b4, const float* g4, const float* be4, const float* m4, const float* v4)
{
    const int bi = blockIdx.x;
    const int t = threadIdx.x;
    if (bi < 1536) {
        int idx = bi * 256 + t;            // B*P*48 (2 ch per thread)
        int c2i = idx % 48;
        int node = idx / 48;
        int p = node & (NP - 1);
        int b = node >> 7;
        int ch0 = c2i * 2, ch1 = ch0 + 1;
        float sa = g0[ch0] * rsqrtf(v0[ch0] + 1e-3f);
        float sb = g0[ch1] * rsqrtf(v0[ch1] + 1e-3f);
        float ca = (b0[ch0] - m0[ch0]) * sa + be0[ch0];
        float cb = (b0[ch1] - m0[ch1]) * sb + be0[ch1];
        const float* xb = x + b * NF * NP + p;
        float r0 = 0.f, r1 = 0.f, s0 = 0.f, s1 = 0.f;
#pragma unroll
        for (int f = 0; f < NF; ++f) {
            float xv = xb[f * NP];
            float2 wr = *(const float2*)&w0[f * 96 + ch0];
            float2 ws = *(const float2*)&w0[(NF + f) * 96 + ch0];
            r0 += xv * wr.x; r1 += xv * wr.y;
            s0 += xv * ws.x; s1 += xv * ws.y;
        }
        f16x2 rv; rv[0] = (_Float16)(r0 * sa + ca); rv[1] = (_Float16)(r1 * sb + cb);
        f16x2 sv; sv[0] = (_Float16)(s0 * sa);      sv[1] = (_Float16)(s1 * sb);
        *(f16x2*)&Rch[node * 96 + ch0] = rv;
        int ks = ch0 >> 5;                 // plane (pair stays within one plane)
        *(f16x2*)&Sc2[((b * 3 + ks) * NP + p) * 32 + (ch0 - ks * 32)] = sv;
    } else if (bi == 1536) {
        if (t < 64) {
            float s = g1[t] * rsqrtf(v1[t] + 1e-3f);
            c1h[t] = (_Float16)((b1[t] - m1[t]) * s + be1[t]);
        }
        if (t < 32) {
            float s = g2[t] * rsqrtf(v2[t] + 1e-3f);
            cs[352 + t] = (b2[t] - m2[t]) * s + be2[t];
        }
        if (t < 64) {
            float s = g3[t] * rsqrtf(v3[t] + 1e-3f);
            c3h[t] = (_Float16)((b3[t] - m3[t]) * s + be3[t]);
        }
        if (t < 32) {
            float s = g4[t] * rsqrtf(v4[t] + 1e-3f);
            cs[512 + t] = (b4[t] - m4[t]) * s + be4[t];
        }
    } else if (bi < 1569) {
        int i = (bi - 1537) * 256 + t;        // 0..8191
        if (i < 6144) {                       // w1f[kb][n][j] = W1[kb*8+j][n]*s1[n]
            int j = i & 7, n = (i >> 3) & 63, kb = i >> 9;
            float s1 = g1[n] * rsqrtf(v1[n] + 1e-3f);
            w1f[i] = (_Float16)(w1[(kb * 8 + j) * 64 + n] * s1);
        } else {                              // w2f: sigma-permuted K, s2-scaled
            int i2 = i - 6144;
            int j = i2 & 7, n = (i2 >> 3) & 31, kb = i2 >> 8;
            int ks = kb >> 2, g = kb & 3;
            int src = (2 * ks + (j >> 2)) * 16 + 4 * g + (j & 3);
            float s2 = g2[n] * rsqrtf(v2[n] + 1e-3f);
            w1f[6144 + i2] = (_Float16)(w2[src * 32 + n] * s2);
        }
    } else if (bi < 1593) {
        int i = (bi - 1569) * 256 + t;        // 0..6143
        if (i < 4096) {                       // w3f[kb][n][j] = fo0[kb*8+j][n]*s3[n], pad k>=48
            int j = i & 7, n = (i >> 3) & 63, kb = i >> 9;
            int k = kb * 8 + j;
            float s3 = g3[n] * rsqrtf(v3[n] + 1e-3f);
            w3f[i] = (k < 48) ? (_Float16)(w3[k * 64 + n] * s3) : (_Float16)0.f;
        } else {                              // w4f: sigma-permuted, s4-scaled
            int i2 = i - 4096;
            int j = i2 & 7, n = (i2 >> 3) & 31, kb = i2 >> 8;
            int ks = kb >> 2, g = kb & 3;
            int src = (2 * ks + (j >> 2)) * 16 + 4 * g + (j & 3);
            float s4 = g4[n] * rsqrtf(v4[n] + 1e-3f);
            w3f[4096 + i2] = (_Float16)(w4[src * 32 + n] * s4);
        }
    } else {
        int n = (bi - 1593) * 256 + t;        // 0..8191 nodes
        int b = n >> 7, pn = n & 127;
        _Float16 tmp[16];
#pragma unroll
        for (int f = 0; f < NF; ++f) tmp[f] = (_Float16)x[(b * NF + f) * NP + pn];
        *(f16x8*)&xt16[n * 16]     = *(f16x8*)&tmp[0];
        *(f16x8*)&xt16[n * 16 + 8] = *(f16x8*)&tmp[8];
    }
}

// ---------------- edge MLP: one wave = one receiver, 128 edges ----------------
// Grid: 2048 blocks x 256 thr = 8192 waves. Block = (b, 4 receivers).
__global__ __launch_bounds__(256) void edge_kernel(
    const _Float16* __restrict__ Rch, const _Float16* __restrict__ Sc2,
    const _Float16* __restrict__ w1f,      // w1f(6144) || w2f(2048)
    const _Float16* __restrict__ c1h, const float* __restrict__ cs,
    float* __restrict__ aggh)              // [node][32] f32
{
    __shared__ _Float16 bw2L[2048];    // fr2 weight frags (4 KB)

    const int tid  = threadIdx.x;
    const int w    = tid >> 6;
    const int lane = tid & 63;
    const int g    = lane >> 4;
    const int l15  = lane & 15;
    const int blk  = blockIdx.x;
    const int b    = blk >> 5;
    const int p    = (blk & 31) * 4 + w;

    // stage fr2 weights to LDS (one uint4 per thread)
    ((uint4*)bw2L)[tid] = ((const uint4*)(w1f + 6144))[tid];
    __syncthreads();

    // ---- fr1 weights + per-lane consts in registers ----
    f16x8 bw1[3][4];
#pragma unroll
    for (int ks = 0; ks < 3; ++ks)
#pragma unroll
        for (int mt = 0; mt < 4; ++mt)
            bw1[ks][mt] = *(const f16x8*)&w1f[(((ks * 4 + g) * 64) + mt * 16 + l15) * 8];
    f16x8 rc[3];
#pragma unroll
    for (int ks = 0; ks < 3; ++ks)
        rc[ks] = *(const f16x8*)&Rch[(size_t)(b * NP + p) * 96 + ks * 32 + g * 8];
    f16x2 c1pk[4][2];
#pragma unroll
    for (int mt = 0; mt < 4; ++mt)
#pragma unroll
        for (int rp = 0; rp < 2; ++rp)
            c1pk[mt][rp] = *(const f16x2*)&c1h[mt * 16 + 4 * g + 2 * rp];
    f32x4 c2v[2];
#pragma unroll
    for (int mt = 0; mt < 2; ++mt)
        c2v[mt] = *(const f32x4*)&cs[352 + mt * 16 + 4 * g];

    f32x4 sums[2];
    sums[0] = (f32x4){0.f, 0.f, 0.f, 0.f};
    sums[1] = (f32x4){0.f, 0.f, 0.f, 0.f};

#pragma unroll
    for (int it = 0; it < 8; ++it) {
        const int row = it * 16 + l15;     // edge (sender) index
        // ---- E1^T B-frag from coalesced k-planes ----
        f16x8 bf[3];
#pragma unroll
        for (int ks = 0; ks < 3; ++ks) {
            f16x8 sv = *(const f16x8*)&Sc2[(size_t)((b * 3 + ks) * NP + row) * 32 + g * 8];
            f16x8 tv = sv + rc[ks];
            f16x8 zz = {};
            bf[ks] = __builtin_elementwise_max(tv, zz);
        }
        // ---- fr1: 12 MFMAs into acc[4] ----
        f32x4 acc[4];
#pragma unroll
        for (int mt = 0; mt < 4; ++mt) acc[mt] = (f32x4){0.f, 0.f, 0.f, 0.f};
#pragma unroll
        for (int ks = 0; ks < 3; ++ks)
#pragma unroll
            for (int mt = 0; mt < 4; ++mt)
                acc[mt] = __builtin_amdgcn_mfma_f32_16x16x32_f16(bw1[ks][mt], bf[ks], acc[mt], 0, 0, 0);
        // ---- epilogue 1 (packed fp16) ----
        f16x2 pw[4][2];
#pragma unroll
        for (int mt = 0; mt < 4; ++mt)
#pragma unroll
            for (int rp = 0; rp < 2; ++rp) {
                f16x2 hh = cvt_pk(acc[mt][2 * rp], acc[mt][2 * rp + 1]);
                hh = hh + c1pk[mt][rp];
                f16x2 zz = {};
                pw[mt][rp] = __builtin_elementwise_max(hh, zz);
            }
        // ---- fr2 via sigma handoff (weights from LDS) ----
        f32x4 acc2[2];
        acc2[0] = (f32x4){0.f, 0.f, 0.f, 0.f};
        acc2[1] = (f32x4){0.f, 0.f, 0.f, 0.f};
#pragma unroll
        for (int ks = 0; ks < 2; ++ks) {
            uint4 uu;
            uu.x = bc32(pw[2 * ks][0]);
            uu.y = bc32(pw[2 * ks][1]);
            uu.z = bc32(pw[2 * ks + 1][0]);
            uu.w = bc32(pw[2 * ks + 1][1]);
            f16x8 u = __builtin_bit_cast(f16x8, uu);
#pragma unroll
            for (int mt = 0; mt < 2; ++mt) {
                f16x8 a2 = *(const f16x8*)&bw2L[(((ks * 4 + g) * 32) + mt * 16 + l15) * 8];
                acc2[mt] = __builtin_amdgcn_mfma_f32_16x16x32_f16(a2, u, acc2[mt], 0, 0, 0);
            }
        }
        // ---- epilogue 2: relu(C2 + c2), accumulate senders != p ----
#pragma unroll
        for (int mt = 0; mt < 2; ++mt)
#pragma unroll
            for (int r = 0; r < 4; ++r) {
                float v = fmaxf(acc2[mt][r] + c2v[mt][r], 0.f);
                sums[mt][r] += (row != p) ? v : 0.f;
            }
    }

    // ---- reduce over the 16 edge-lanes within each group; store partials ----
#pragma unroll
    for (int mt = 0; mt < 2; ++mt)
#pragma unroll
        for (int d = 1; d <= 8; d <<= 1) {
            sums[mt][0] += __shfl_xor(sums[mt][0], d, 64);
            sums[mt][1] += __shfl_xor(sums[mt][1], d, 64);
            sums[mt][2] += __shfl_xor(sums[mt][2], d, 64);
            sums[mt][3] += __shfl_xor(sums[mt][3], d, 64);
        }
    if (l15 == 0) {
#pragma unroll
        for (int mt = 0; mt < 2; ++mt)
            *(f32x4*)&aggh[(size_t)(b * NP + p) * 32 + mt * 16 + 4 * g] = sums[mt];
    }
}

// ---------------- fo MLP + batch reduce, fused ----------------
// Grid: 64 blocks (one per batch) x 256 thr = 4 waves; wave w, pass q:
// nodes w*32 + q*16 + l15.
__global__ __launch_bounds__(256) void fo_reduce_kernel(
    const float* __restrict__ aggh, const _Float16* __restrict__ xt16,
    const _Float16* __restrict__ w3f,      // w3f(4096) || w4f(2048)
    const _Float16* __restrict__ c3h, const float* __restrict__ cs,
    float* __restrict__ out)
{
    __shared__ float red[128][33];
    __shared__ float red2[256];

    const int tid  = threadIdx.x;
    const int w    = tid >> 6;
    const int lane = tid & 63;
    const int g    = lane >> 4;
    const int l15  = lane & 15;
    const int b    = blockIdx.x;

#pragma unroll
    for (int q = 0; q < 2; ++q) {
        const int nl = w * 32 + q * 16 + l15;      // node-in-batch 0..127
        const size_t node = (size_t)b * NP + nl;

        // ---- B-frags of H^T: k 0..15 = x, 16..47 = agg, 48..63 = 0 ----
        f16x8 bfo[2];
        if (g < 2) {
            bfo[0] = *(const f16x8*)&xt16[node * 16 + g * 8];
            const float* a1 = &aggh[node * 32 + 16 + g * 8];   // k=32+g*8+j -> col 16+g*8+j
            f16x8 t1;
#pragma unroll
            for (int j = 0; j < 8; ++j) t1[j] = (_Float16)a1[j];
            bfo[1] = t1;
        } else {
            const float* a0 = &aggh[node * 32 + (g - 2) * 8];  // k=g*8+j -> col (g-2)*8+j
            f16x8 t0;
#pragma unroll
            for (int j = 0; j < 8; ++j) t0[j] = (_Float16)a0[j];
            bfo[0] = t0;
            f16x8 zz = {};
            bfo[1] = zz;
        }

        // ---- fo0: C3^T = W3^T x H^T ----
        f32x4 acc3[4];
#pragma unroll
        for (int mt = 0; mt < 4; ++mt) acc3[mt] = (f32x4){0.f, 0.f, 0.f, 0.f};
#pragma unroll
        for (int ks = 0; ks < 2; ++ks)
#pragma unroll
            for (int mt = 0; mt < 4; ++mt) {
                f16x8 a3 = *(const f16x8*)&w3f[(((ks * 4 + g) * 64) + mt * 16 + l15) * 8];
                acc3[mt] = __builtin_amdgcn_mfma_f32_16x16x32_f16(a3, bfo[ks], acc3[mt], 0, 0, 0);
            }
        f16x2 pw3[4][2];
#pragma unroll
        for (int mt = 0; mt < 4; ++mt)
#pragma unroll
            for (int rp = 0; rp < 2; ++rp) {
                f16x2 hh = cvt_pk(acc3[mt][2 * rp], acc3[mt][2 * rp + 1]);
                hh = hh + *(const f16x2*)&c3h[mt * 16 + 4 * g + 2 * rp];
                f16x2 zz = {};
                pw3[mt][rp] = __builtin_elementwise_max(hh, zz);
            }
        // ---- fo1 via sigma handoff ----
        f32x4 acc4[2];
        acc4[0] = (f32x4){0.f, 0.f, 0.f, 0.f};
        acc4[1] = (f32x4){0.f, 0.f, 0.f, 0.f};
#pragma unroll
        for (int ks = 0; ks < 2; ++ks) {
            uint4 uu;
            uu.x = bc32(pw3[2 * ks][0]);
            uu.y = bc32(pw3[2 * ks][1]);
            uu.z = bc32(pw3[2 * ks + 1][0]);
            uu.w = bc32(pw3[2 * ks + 1][1]);
            f16x8 u = __builtin_bit_cast(f16x8, uu);
#pragma unroll
            for (int mt = 0; mt < 2; ++mt) {
                f16x8 a4 = *(const f16x8*)&w3f[4096 + (((ks * 4 + g) * 32) + mt * 16 + l15) * 8];
                acc4[mt] = __builtin_amdgcn_mfma_f32_16x16x32_f16(a4, u, acc4[mt], 0, 0, 0);
            }
        }
        // ---- epilogue: relu(C4 + c4) -> LDS ----
#pragma unroll
        for (int mt = 0; mt < 2; ++mt) {
            f32x4 c4 = *(const f32x4*)&cs[512 + mt * 16 + 4 * g];
#pragma unroll
            for (int r = 0; r < 4; ++r)
                red[nl][mt * 16 + 4 * g + r] = fmaxf(acc4[mt][r] + c4[r], 0.f);
        }
    }
    __syncthreads();

    // ---- reduce 128 nodes -> out[b][32] ----
    int m = tid & 31;
    int grp = tid >> 5;                // 8 groups
    float v = 0.f;
#pragma unroll
    for (int pn = 0; pn < 16; ++pn) v += red[grp * 16 + pn][m];
    red2[tid] = v;
    __syncthreads();
    if (grp < 4) red2[tid] += red2[tid + 128];
    __syncthreads();
    if (grp < 2) red2[tid] += red2[tid + 64];
    __syncthreads();
    if (grp == 0) out[b * 32 + m] = red2[tid] + red2[tid + 32];
}

extern "C" void kernel_launch(void* const* d_in, const int* in_sizes, int n_in,
                              void* d_out, int out_size, void* d_ws, size_t ws_size,
                              hipStream_t stream) {
    (void)in_sizes; (void)n_in; (void)out_size; (void)ws_size;
    const float* x    = (const float*)d_in[0];
    const float* fr0w = (const float*)d_in[1];
    const float* fr1w = (const float*)d_in[7];
    const float* fr2w = (const float*)d_in[13];
    const float* fo0w = (const float*)d_in[19];
    const float* fo1w = (const float*)d_in[25];

    float* ws = (float*)d_ws;
    float*    cs     = ws;                                   // 1024 f32
    _Float16* Rch    = (_Float16*)(ws + 1024);               // 786432 f16
    _Float16* Sc2    = (_Float16*)(ws + 394240);             // 786432 f16
    _Float16* w1f    = (_Float16*)(ws + 787456);             // 8192 f16 (w1f||w2f)
    _Float16* w3f    = (_Float16*)(ws + 791552);             // 6144 f16 (w3f||w4f)
    _Float16* c1h    = (_Float16*)(ws + 794624);             // 64 f16
    _Float16* c3h    = c1h + 64;                             // 64 f16
    _Float16* xt16   = (_Float16*)(ws + 794688);             // 131072 f16
    float*    aggh   = ws + 860224;                          // 8192*32 f32
    float*    out    = (float*)d_out;

    prep_kernel<<<1625, 256, 0, stream>>>(x, fr0w, fr1w, fr2w, fo0w, fo1w,
        w1f, w3f, cs, c1h, c3h, xt16, Rch, Sc2,
        (const float*)d_in[2],  (const float*)d_in[3],  (const float*)d_in[4],
        (const float*)d_in[5],  (const float*)d_in[6],
        (const float*)d_in[8],  (const float*)d_in[9],  (const float*)d_in[10],
        (const float*)d_in[11], (const float*)d_in[12],
        (const float*)d_in[14], (const float*)d_in[15], (const float*)d_in[16],
        (const float*)d_in[17], (const float*)d_in[18],
        (const float*)d_in[20], (const float*)d_in[21], (const float*)d_in[22],
        (const float*)d_in[23], (const float*)d_in[24],
        (const float*)d_in[26], (const float*)d_in[27], (const float*)d_in[28],
        (const float*)d_in[29], (const float*)d_in[30]);

    edge_kernel<<<NB * 32, 256, 0, stream>>>(Rch, Sc2, w1f, c1h, cs, aggh);

    fo_reduce_kernel<<<NB, 256, 0, stream>>>(aggh, xt16, w3f, c3h, cs, out);
}